// Round 4
// baseline (267.344 us; speedup 1.0000x reference)
//
#include <hip/hip_runtime.h>

#define NTOK 4608   // token axis N = H*W/2
#define CCH  64     // feature axis C
#define HWSZ 9216   // H*W
#define NB   4      // batch
#define NSPL 8      // passA n-split
#define L2E  1.4426950408889634f

typedef unsigned short u16;
typedef __attribute__((ext_vector_type(4))) short s16x4;   // 4 bf16
typedef __attribute__((ext_vector_type(8))) short s16x8;   // 8 bf16
typedef __attribute__((ext_vector_type(4))) float f32x4;

__device__ __forceinline__ f32x4 mfma16(s16x8 a, s16x8 b, f32x4 c){
  return __builtin_amdgcn_mfma_f32_16x16x32_bf16(a, b, c, 0, 0, 0);
}
__device__ __forceinline__ u16 f2bf(float f){
  unsigned int u = __float_as_uint(f);
  u += 0x7fffu + ((u >> 16) & 1u);   // RNE
  return (u16)(u >> 16);
}
#define SB() __builtin_amdgcn_sched_barrier(0)
union GU { s16x8 v; struct { s16x4 lo, hi; } p; };

// ---------------------------------------------------------------------------
// Kernel 1: fused theta/phi/g projections. theta is pre-scaled by log2(e) so
// downstream softmax works in exp2 domain with zero extra VALU.
// TH/PH[b][pos][c] bf16; G[b][c][m] bf16.
// ---------------------------------------------------------------------------
__global__ __launch_bounds__(512) void proj_kernel(
    const float* __restrict__ x, const float* __restrict__ y,
    const float* __restrict__ w_phi, const float* __restrict__ w_theta,
    const float* __restrict__ w_g,
    u16* __restrict__ TH, u16* __restrict__ PH, u16* __restrict__ G){
  const int b = blockIdx.y;
  const int n = blockIdx.x*64 + (threadIdx.x & 63);
  const int wq = __builtin_amdgcn_readfirstlane((int)(threadIdx.x >> 6)); // 0..7
  const float* xb = x + (size_t)b*CCH*HWSZ;
  const float* yb = y + (size_t)b*CCH*HWSZ;
  const float* wp = w_phi   + wq*4*CCH;
  const float* wt = w_theta + wq*4*CCH;
  const float* wg = w_g     + wq*4*CCH;
  float accP[8], accT[8], accG[8];
  #pragma unroll
  for(int j=0;j<8;++j){ accP[j]=0.f; accT[j]=0.f; accG[j]=0.f; }
  for(int k=0;k<CCH;k+=4){
    float xv0[4], xv1[4], yv0[4], yv1[4];
    #pragma unroll
    for(int u=0;u<4;++u){
      xv0[u] = xb[(size_t)(k+u)*HWSZ + n];
      xv1[u] = xb[(size_t)(k+u)*HWSZ + NTOK + n];
      yv0[u] = yb[(size_t)(k+u)*HWSZ + n];
      yv1[u] = yb[(size_t)(k+u)*HWSZ + NTOK + n];
    }
    #pragma unroll
    for(int u=0;u<4;++u)
      #pragma unroll
      for(int j=0;j<8;++j){
        float xv = (j&1)?xv1[u]:xv0[u];
        accP[j] = fmaf(wp[(j>>1)*CCH + k+u], xv, accP[j]);
        accT[j] = fmaf(wt[(j>>1)*CCH + k+u], (j&1)?yv1[u]:yv0[u], accT[j]);
        accG[j] = fmaf(wg[(j>>1)*CCH + k+u], xv, accG[j]);
      }
  }
  s16x8 vp, vt;
  #pragma unroll
  for(int j=0;j<8;++j){
    vp[j]=(short)f2bf(accP[j]);
    vt[j]=(short)f2bf(accT[j]*L2E);    // exp2-domain pre-scale
  }
  *(s16x8*)(PH + ((size_t)b*NTOK + n)*CCH + wq*8) = vp;
  *(s16x8*)(TH + ((size_t)b*NTOK + n)*CCH + wq*8) = vt;
  #pragma unroll
  for(int j=0;j<8;++j)
    G[((size_t)b*CCH + wq*8 + j)*NTOK + n] = f2bf(accG[j]);
}

// ---------------------------------------------------------------------------
// Kernel 2: pass A — per-column sum of exp2(S'), S' = (theta*log2e)^T phi.
// Wave owns 32 m-cols; streams TH rows, 2-deep register pipeline PINNED with
// sched_barrier(0) so the compiler cannot sink the prefetch loads.
// ---------------------------------------------------------------------------
__global__ __launch_bounds__(256, 4) void passA_kernel(
    const u16* __restrict__ TH, const u16* __restrict__ PH,
    float* __restrict__ CSUMP){
  const int bid = blockIdx.x;
  const int xcd = bid & 7, b = xcd >> 1;
  const int j = ((bid >> 3) << 1) | (xcd & 1);   // [0, 36*NSPL)
  const int part = j & (NSPL-1);
  const int mb = j >> 3;                          // NSPL == 8
  const int lane = threadIdx.x & 63, wave = threadIdx.x >> 6;
  const int l15 = lane & 15, lg = lane >> 4;
  const int mbase = mb*128 + wave*32;
  const u16* thb = TH + (size_t)b*NTOK*CCH;
  const u16* phb = PH + (size_t)b*NTOK*CCH;
  const u16* p0 = phb + (size_t)(mbase + l15)*CCH + lg*8;
  const u16* p1 = p0 + 16*CCH;
  s16x8 bf00 = *(const s16x8*)p0, bf01 = *(const s16x8*)(p0+32);
  s16x8 bf10 = *(const s16x8*)p1, bf11 = *(const s16x8*)(p1+32);
  float rs0 = 0.f, rs1 = 0.f;
  const int ncount = NTOK/NSPL;    // 576 = 9 x 64
  const int n0 = part*ncount;
  s16x8 aA[8], aB[8];

  auto LOADA = [&](int n){
    #pragma unroll
    for(int s=0;s<4;++s){
      const u16* ar = thb + (size_t)(n + s*16 + l15)*CCH + lg*8;
      aA[2*s] = *(const s16x8*)ar; aA[2*s+1] = *(const s16x8*)(ar+32);
    }
  };
  auto LOADB = [&](int n){
    #pragma unroll
    for(int s=0;s<4;++s){
      const u16* ar = thb + (size_t)(n + s*16 + l15)*CCH + lg*8;
      aB[2*s] = *(const s16x8*)ar; aB[2*s+1] = *(const s16x8*)(ar+32);
    }
  };
  auto COMP = [&](const s16x8* a){
    #pragma unroll
    for(int s=0;s<4;++s){
      f32x4 v0 = {0.f,0.f,0.f,0.f}, v1 = {0.f,0.f,0.f,0.f};
      v0 = mfma16(a[2*s], bf00, v0); v0 = mfma16(a[2*s+1], bf01, v0);
      v1 = mfma16(a[2*s], bf10, v1); v1 = mfma16(a[2*s+1], bf11, v1);
      rs0 += (exp2f(v0[0])+exp2f(v0[1])) + (exp2f(v0[2])+exp2f(v0[3]));
      rs1 += (exp2f(v1[0])+exp2f(v1[1])) + (exp2f(v1[2])+exp2f(v1[3]));
    }
  };

  LOADA(n0);
  int n = n0;
  #pragma unroll 1
  for(int t=0; t<4; ++t){          // 8 of 9 64-row steps, pipelined
    SB(); LOADB(n + 64);
    SB(); COMP(aA);
    SB(); LOADA(n + 128);          // t==3: n0+512, valid
    SB(); COMP(aB);
    n += 128;
  }
  SB(); COMP(aA);                  // 9th step

  rs0 += __shfl_xor(rs0, 16); rs0 += __shfl_xor(rs0, 32);
  rs1 += __shfl_xor(rs1, 16); rs1 += __shfl_xor(rs1, 32);
  if(lg == 0){
    float* dst = CSUMP + (size_t)(part*NB + b)*NTOK + mbase;
    dst[l15]      = rs0;
    dst[16 + l15] = rs1;
  }
}

// ---------------------------------------------------------------------------
// Kernel 3: merge NSPL partial sums -> COFF[m] = -log2(sum).
// ---------------------------------------------------------------------------
__global__ __launch_bounds__(256) void merge_stats_kernel(
    const float* __restrict__ CSUMP, float* __restrict__ COFF){
  const int i = blockIdx.x*256 + threadIdx.x;
  if(i >= NB*NTOK) return;
  float s = 0.f;
  #pragma unroll
  for(int h=0; h<NSPL; ++h) s += CSUMP[h*NB*NTOK + i];
  COFF[i] = -log2f(s);
}

// ---------------------------------------------------------------------------
// Kernel 4: pass B — swapped-operand S recompute; P = exp2(S' + COFF).
// 2 n-tiles per wave share all streamed loads; 2-deep register pipeline
// pinned with sched_barrier(0); COFF loads hoisted into the load phase so
// no compute-phase load can force a vmcnt(0) drain of the prefetch queue.
// ---------------------------------------------------------------------------
template<int MSPLIT>
__global__ __launch_bounds__(256, 3) void passB_kernel(
    const u16* __restrict__ TH, const u16* __restrict__ PH,
    const u16* __restrict__ G, const float* __restrict__ COFF,
    float* __restrict__ OUTP){
  const int bid = blockIdx.x;
  const int xcd = bid & 7, b = xcd >> 1;
  const int j = ((bid >> 3) << 1) | (xcd & 1);   // [0, 36*MSPLIT)
  const int mpart = j & (MSPLIT-1);
  const int nb = j / MSPLIT;                      // [0, 36)
  const int lane = threadIdx.x & 63, wave = threadIdx.x >> 6;
  const int l15 = lane & 15, lg = lane >> 4;
  const int nbase = nb*128 + wave*32;
  const u16* thb = TH + (size_t)b*NTOK*CCH;
  const u16* phb = PH + (size_t)b*NTOK*CCH;
  const u16* gbb = G  + (size_t)b*CCH*NTOK;
  const float* coffb = COFF + (size_t)b*NTOK;
  const u16* t0 = thb + (size_t)(nbase + l15)*CCH + lg*8;
  const u16* t1 = t0 + 16*CCH;
  s16x8 bt00 = *(const s16x8*)t0, bt01 = *(const s16x8*)(t0+32);
  s16x8 bt10 = *(const s16x8*)t1, bt11 = *(const s16x8*)(t1+32);
  f32x4 acc[2][4];
  #pragma unroll
  for(int tt=0;tt<2;++tt)
    #pragma unroll
    for(int ct=0;ct<4;++ct) acc[tt][ct] = (f32x4){0.f,0.f,0.f,0.f};

  const int mcnt = NTOK/MSPLIT;
  const int m0 = mpart*mcnt;
  s16x8 apA[4], apB[4];
  GU gA[4], gB[4];
  f32x4 coA0, coA1, coB0, coB1;

  auto LOADA = [&](int m){
    const u16* pr0 = phb + (size_t)(m + l15)*CCH + lg*8;
    const u16* pr1 = pr0 + 16*CCH;
    apA[0]=*(const s16x8*)pr0; apA[1]=*(const s16x8*)(pr0+32);
    apA[2]=*(const s16x8*)pr1; apA[3]=*(const s16x8*)(pr1+32);
    #pragma unroll
    for(int ct=0;ct<4;++ct){
      const u16* grow = gbb + (size_t)(ct*16 + l15)*NTOK + m + lg*4;
      gA[ct].p.lo = *(const s16x4*)grow;
      gA[ct].p.hi = *(const s16x4*)(grow + 16);
    }
    coA0 = *(const f32x4*)(coffb + m + lg*4);
    coA1 = *(const f32x4*)(coffb + m + 16 + lg*4);
  };
  auto LOADBf = [&](int m){
    const u16* pr0 = phb + (size_t)(m + l15)*CCH + lg*8;
    const u16* pr1 = pr0 + 16*CCH;
    apB[0]=*(const s16x8*)pr0; apB[1]=*(const s16x8*)(pr0+32);
    apB[2]=*(const s16x8*)pr1; apB[3]=*(const s16x8*)(pr1+32);
    #pragma unroll
    for(int ct=0;ct<4;++ct){
      const u16* grow = gbb + (size_t)(ct*16 + l15)*NTOK + m + lg*4;
      gB[ct].p.lo = *(const s16x4*)grow;
      gB[ct].p.hi = *(const s16x4*)(grow + 16);
    }
    coB0 = *(const f32x4*)(coffb + m + lg*4);
    coB1 = *(const f32x4*)(coffb + m + 16 + lg*4);
  };
  auto COMP = [&](const s16x8* ap, const GU* g, const f32x4& co0,
                  const f32x4& co1){
    f32x4 s00={0.f,0.f,0.f,0.f}, s01={0.f,0.f,0.f,0.f};
    f32x4 s10={0.f,0.f,0.f,0.f}, s11={0.f,0.f,0.f,0.f};
    s00 = mfma16(ap[0], bt00, s00); s00 = mfma16(ap[1], bt01, s00);
    s01 = mfma16(ap[2], bt00, s01); s01 = mfma16(ap[3], bt01, s01);
    s10 = mfma16(ap[0], bt10, s10); s10 = mfma16(ap[1], bt11, s10);
    s11 = mfma16(ap[2], bt10, s11); s11 = mfma16(ap[3], bt11, s11);
    s16x8 pa0, pa1;
    #pragma unroll
    for(int r=0;r<4;++r){
      pa0[r]   = (short)f2bf(exp2f(s00[r] + co0[r]));
      pa0[4+r] = (short)f2bf(exp2f(s01[r] + co1[r]));
      pa1[r]   = (short)f2bf(exp2f(s10[r] + co0[r]));
      pa1[4+r] = (short)f2bf(exp2f(s11[r] + co1[r]));
    }
    #pragma unroll
    for(int ct=0;ct<4;++ct){
      acc[0][ct] = mfma16(pa0, g[ct].v, acc[0][ct]);
      acc[1][ct] = mfma16(pa1, g[ct].v, acc[1][ct]);
    }
  };

  LOADA(m0);
  #pragma unroll 1
  for(int m = m0; m < m0 + mcnt; m += 64){
    SB(); LOADBf(m + 32);
    SB(); COMP(apA, gA, coA0, coA1);
    const int mn = (m + 64 < m0 + mcnt) ? m + 64 : m0;   // clamped prefetch
    SB(); LOADA(mn);
    SB(); COMP(apB, gB, coB0, coB1);
  }
  SB();

  float* outp = OUTP + ((size_t)(mpart*NB + b)*NTOK)*CCH;
  #pragma unroll
  for(int tt=0;tt<2;++tt)
    #pragma unroll
    for(int ct=0;ct<4;++ct)
      #pragma unroll
      for(int r=0;r<4;++r)
        outp[(size_t)(nbase + tt*16 + lg*4 + r)*CCH + ct*16 + l15] = acc[tt][ct][r];
}

// ---------------------------------------------------------------------------
// Kernel 5: sum m-partials, apply w_mask 1x1 conv, add x.
// ---------------------------------------------------------------------------
template<int MSPLIT>
__global__ __launch_bounds__(256) void finalize_kernel(
    const float* __restrict__ OUTP, const float* __restrict__ w_mask,
    const float* __restrict__ x, float* __restrict__ out){
  const int b = blockIdx.y;
  const int n = blockIdx.x*64 + (threadIdx.x & 63);
  const int q = __builtin_amdgcn_readfirstlane((int)(threadIdx.x >> 6));
  float v[64];
  #pragma unroll
  for(int c=0;c<64;++c) v[c] = 0.f;
  #pragma unroll
  for(int h=0; h<MSPLIT; ++h){
    const f32x4* r = (const f32x4*)(OUTP + ((size_t)(h*NB + b)*NTOK + n)*CCH);
    #pragma unroll
    for(int t=0;t<16;++t){
      f32x4 u = r[t];
      v[4*t]+=u[0]; v[4*t+1]+=u[1]; v[4*t+2]+=u[2]; v[4*t+3]+=u[3];
    }
  }
  const float* wm = w_mask + q*16*32;   // wave-uniform -> s_loads
  #pragma unroll
  for(int jj=0;jj<16;++jj){
    float a0 = 0.f, a1 = 0.f;
    #pragma unroll
    for(int ic=0;ic<32;++ic){
      float w = wm[jj*32 + ic];
      a0 = fmaf(w, v[2*ic],   a0);
      a1 = fmaf(w, v[2*ic+1], a1);
    }
    const size_t idx = ((size_t)b*CCH + q*16 + jj)*HWSZ + n;
    out[idx]        = a0 + x[idx];
    out[idx + NTOK] = a1 + x[idx + NTOK];
  }
}

// ---------------------------------------------------------------------------
extern "C" void kernel_launch(void* const* d_in, const int* in_sizes, int n_in,
                              void* d_out, int out_size, void* d_ws, size_t ws_size,
                              hipStream_t stream){
  const float* x       = (const float*)d_in[0];
  const float* y       = (const float*)d_in[1];
  const float* w_phi   = (const float*)d_in[2];
  const float* w_theta = (const float*)d_in[3];
  const float* w_g     = (const float*)d_in[4];
  const float* w_mask  = (const float*)d_in[5];
  float* out = (float*)d_out;
  char* ws = (char*)d_ws;

  const size_t projB  = (size_t)NB*NTOK*CCH*sizeof(u16);    // 2,359,296
  const size_t outpB1 = (size_t)NB*NTOK*CCH*sizeof(float);  // 4,718,592 per split
  const size_t fstat  = (size_t)NB*NTOK*sizeof(float);      // 73,728
  const size_t fixed  = 3*projB + (size_t)NSPL*fstat + fstat;

  int msplit = (ws_size >= fixed + 8*outpB1) ? 8
             : (ws_size >= fixed + 4*outpB1) ? 4
             : (ws_size >= fixed + 2*outpB1) ? 2 : 1;

  size_t off = 0;
  u16*   TH    = (u16*)(ws + off); off += projB;
  u16*   PH    = (u16*)(ws + off); off += projB;
  u16*   G     = (u16*)(ws + off); off += projB;
  float* OUTP  = (float*)(ws + off); off += (size_t)msplit*outpB1;
  float* CSUMP = (float*)(ws + off); off += (size_t)NSPL*fstat;
  float* COFF  = (float*)(ws + off); off += fstat;

  proj_kernel<<<dim3(NTOK/64, NB), 512, 0, stream>>>(x, y, w_phi, w_theta, w_g,
                                                     TH, PH, G);
  passA_kernel<<<dim3((NTOK/128)*NSPL*NB), 256, 0, stream>>>(TH, PH, CSUMP);
  merge_stats_kernel<<<dim3((NB*NTOK)/256), 256, 0, stream>>>(CSUMP, COFF);
  const int gB = (NTOK/128)*msplit*NB;
  switch(msplit){
    case 8: passB_kernel<8><<<dim3(gB),256,0,stream>>>(TH,PH,G,COFF,OUTP); break;
    case 4: passB_kernel<4><<<dim3(gB),256,0,stream>>>(TH,PH,G,COFF,OUTP); break;
    case 2: passB_kernel<2><<<dim3(gB),256,0,stream>>>(TH,PH,G,COFF,OUTP); break;
    default: passB_kernel<1><<<dim3(gB),256,0,stream>>>(TH,PH,G,COFF,OUTP); break;
  }
  switch(msplit){
    case 8: finalize_kernel<8><<<dim3(NTOK/64,NB),256,0,stream>>>(OUTP,w_mask,x,out); break;
    case 4: finalize_kernel<4><<<dim3(NTOK/64,NB),256,0,stream>>>(OUTP,w_mask,x,out); break;
    case 2: finalize_kernel<2><<<dim3(NTOK/64,NB),256,0,stream>>>(OUTP,w_mask,x,out); break;
    default: finalize_kernel<1><<<dim3(NTOK/64,NB),256,0,stream>>>(OUTP,w_mask,x,out); break;
  }
}

// Round 5
// 145.933 us; speedup vs baseline: 1.8320x; 1.8320x over previous
//
#include <hip/hip_runtime.h>

#define NTOK 4608   // token axis N = H*W/2
#define CCH  64     // feature axis C
#define HWSZ 9216   // H*W
#define NB   4      // batch
#define NSPL 8      // passA n-split
#define L2E  1.4426950408889634f

typedef unsigned short u16;
typedef __attribute__((ext_vector_type(4))) short s16x4;   // 4 bf16
typedef __attribute__((ext_vector_type(8))) short s16x8;   // 8 bf16
typedef __attribute__((ext_vector_type(4))) float f32x4;

__device__ __forceinline__ f32x4 mfma16(s16x8 a, s16x8 b, f32x4 c){
  return __builtin_amdgcn_mfma_f32_16x16x32_bf16(a, b, c, 0, 0, 0);
}
__device__ __forceinline__ u16 f2bf(float f){
  unsigned int u = __float_as_uint(f);
  u += 0x7fffu + ((u >> 16) & 1u);   // RNE
  return (u16)(u >> 16);
}
__device__ __forceinline__ float bf2f(u16 h){
  return __uint_as_float(((unsigned int)h) << 16);
}
union GU { s16x8 v; struct { s16x4 lo, hi; } p; };

// global -> LDS direct copy, 16B per lane. LDS dest = wave-uniform base +
// lane*16 (HW rule); global src is per-lane (pre-swizzled for bank-free reads).
__device__ __forceinline__ void gload16(const void* g, void* l){
  __builtin_amdgcn_global_load_lds(
      (const __attribute__((address_space(1))) void*)g,
      (__attribute__((address_space(3))) void*)l, 16, 0, 0);
}
#define SBAR() __builtin_amdgcn_sched_barrier(0)
#define WAITVM(N) do{ SBAR(); asm volatile("s_waitcnt vmcnt(" #N ")" ::: "memory"); SBAR(); }while(0)

// ---------------------------------------------------------------------------
// Kernel 1: fused theta/phi/g projections. theta pre-scaled by log2(e).
// TH/PH[b][pos][c] bf16; G[b][c][m] bf16.
// ---------------------------------------------------------------------------
__global__ __launch_bounds__(512) void proj_kernel(
    const float* __restrict__ x, const float* __restrict__ y,
    const float* __restrict__ w_phi, const float* __restrict__ w_theta,
    const float* __restrict__ w_g,
    u16* __restrict__ TH, u16* __restrict__ PH, u16* __restrict__ G){
  const int b = blockIdx.y;
  const int n = blockIdx.x*64 + (threadIdx.x & 63);
  const int wq = __builtin_amdgcn_readfirstlane((int)(threadIdx.x >> 6)); // 0..7
  const float* xb = x + (size_t)b*CCH*HWSZ;
  const float* yb = y + (size_t)b*CCH*HWSZ;
  const float* wp = w_phi   + wq*4*CCH;
  const float* wt = w_theta + wq*4*CCH;
  const float* wg = w_g     + wq*4*CCH;
  float accP[8], accT[8], accG[8];
  #pragma unroll
  for(int j=0;j<8;++j){ accP[j]=0.f; accT[j]=0.f; accG[j]=0.f; }
  for(int k=0;k<CCH;k+=4){
    float xv0[4], xv1[4], yv0[4], yv1[4];
    #pragma unroll
    for(int u=0;u<4;++u){
      xv0[u] = xb[(size_t)(k+u)*HWSZ + n];
      xv1[u] = xb[(size_t)(k+u)*HWSZ + NTOK + n];
      yv0[u] = yb[(size_t)(k+u)*HWSZ + n];
      yv1[u] = yb[(size_t)(k+u)*HWSZ + NTOK + n];
    }
    #pragma unroll
    for(int u=0;u<4;++u)
      #pragma unroll
      for(int j=0;j<8;++j){
        float xv = (j&1)?xv1[u]:xv0[u];
        accP[j] = fmaf(wp[(j>>1)*CCH + k+u], xv, accP[j]);
        accT[j] = fmaf(wt[(j>>1)*CCH + k+u], (j&1)?yv1[u]:yv0[u], accT[j]);
        accG[j] = fmaf(wg[(j>>1)*CCH + k+u], xv, accG[j]);
      }
  }
  s16x8 vp, vt;
  #pragma unroll
  for(int j=0;j<8;++j){
    vp[j]=(short)f2bf(accP[j]);
    vt[j]=(short)f2bf(accT[j]*L2E);    // exp2-domain pre-scale
  }
  *(s16x8*)(PH + ((size_t)b*NTOK + n)*CCH + wq*8) = vp;
  *(s16x8*)(TH + ((size_t)b*NTOK + n)*CCH + wq*8) = vt;
  #pragma unroll
  for(int j=0;j<8;++j)
    G[((size_t)b*CCH + wq*8 + j)*NTOK + n] = f2bf(accG[j]);
}

// ---------------------------------------------------------------------------
// Kernel 2: pass A — per-column sum of exp2(S'). TH chunks (32 n-rows, 4KB)
// staged into LDS once per block (shared by 4 waves), 4-buffer ring,
// stage-ahead-2, counted vmcnt(2), raw s_barrier. XOR-swizzled (slot^=row&7)
// via pre-swizzled global source; ds_read_b128 conflict-free.
// ---------------------------------------------------------------------------
__global__ __launch_bounds__(256, 4) void passA_kernel(
    const u16* __restrict__ TH, const u16* __restrict__ PH,
    float* __restrict__ CSUMP){
  __shared__ __align__(16) u16 ldsTH[4*2048];     // 4 bufs x 4KB
  const int bid = blockIdx.x;
  const int xcd = bid & 7, b = xcd >> 1;
  const int j = ((bid >> 3) << 1) | (xcd & 1);    // [0, 36*NSPL)
  const int part = j & (NSPL-1);
  const int mt = j >> 3;                           // NSPL == 8
  const int lane = threadIdx.x & 63;
  const int wq = __builtin_amdgcn_readfirstlane((int)(threadIdx.x >> 6));
  const int l15 = lane & 15, lg = lane >> 4;
  const int mbase = mt*128 + wq*32;
  const u16* thb = TH + (size_t)b*NTOK*CCH;
  const u16* phb = PH + (size_t)b*NTOK*CCH;
  // hoisted PH B-frags: 2 m-tiles of 16
  const u16* p0 = phb + (size_t)(mbase + l15)*CCH + lg*8;
  const u16* p1 = p0 + 16*CCH;
  s16x8 bf00 = *(const s16x8*)p0, bf01 = *(const s16x8*)(p0+32);
  s16x8 bf10 = *(const s16x8*)p1, bf11 = *(const s16x8*)(p1+32);
  float rs0 = 0.f, rs1 = 0.f;

  const int NCH = (NTOK/NSPL)/32;                  // 18
  const int n0 = part*(NTOK/NSPL);
  // stage chunk ci into buffer bi (1 gload16 per wave = wave's 8 rows)
  const int srl = wq*8 + (lane>>3);                // local row this lane stages
  const int ssl = (lane&7) ^ (srl&7);              // pre-swizzled 16B slot
  auto STAGE = [&](int ci, int bi){
    const u16* src = thb + (size_t)(n0 + ci*32 + srl)*CCH + ssl*8;
    gload16(src, ldsTH + bi*2048 + wq*512);
  };

  STAGE(0, 0); STAGE(1, 1);
  #pragma unroll 1
  for(int t=0; t<NCH; ++t){
    int ci = t+2; if(ci >= NCH) ci -= NCH;         // dummy wrap (unused data)
    STAGE(ci, (t+2)&3);
    WAITVM(2);
    __builtin_amdgcn_s_barrier();
    const u16* bTH = ldsTH + (t&3)*2048;
    #pragma unroll
    for(int s=0;s<2;++s){
      const int r = s*16 + l15, rx = r & 7;
      const u16* rb = bTH + r*64;
      s16x8 a0 = *(const s16x8*)(rb + ((lg     ^ rx)<<3));
      s16x8 a1 = *(const s16x8*)(rb + (((lg+4) ^ rx)<<3));
      f32x4 v0 = {0.f,0.f,0.f,0.f}, v1 = {0.f,0.f,0.f,0.f};
      v0 = mfma16(a0, bf00, v0); v0 = mfma16(a1, bf01, v0);
      v1 = mfma16(a0, bf10, v1); v1 = mfma16(a1, bf11, v1);
      rs0 += (exp2f(v0[0])+exp2f(v0[1])) + (exp2f(v0[2])+exp2f(v0[3]));
      rs1 += (exp2f(v1[0])+exp2f(v1[1])) + (exp2f(v1[2])+exp2f(v1[3]));
    }
  }

  rs0 += __shfl_xor(rs0, 16); rs0 += __shfl_xor(rs0, 32);
  rs1 += __shfl_xor(rs1, 16); rs1 += __shfl_xor(rs1, 32);
  if(lg == 0){
    float* dst = CSUMP + (size_t)(part*NB + b)*NTOK + mbase;
    dst[l15]      = rs0;
    dst[16 + l15] = rs1;
  }
}

// ---------------------------------------------------------------------------
// Kernel 3: merge NSPL partial sums -> DINV[m] = 1/sum.
// ---------------------------------------------------------------------------
__global__ __launch_bounds__(256) void merge_stats_kernel(
    const float* __restrict__ CSUMP, float* __restrict__ DINV){
  const int i = blockIdx.x*256 + threadIdx.x;
  if(i >= NB*NTOK) return;
  float s = 0.f;
  #pragma unroll
  for(int h=0; h<NSPL; ++h) s += CSUMP[h*NB*NTOK + i];
  DINV[i] = 1.0f / s;
}

// ---------------------------------------------------------------------------
// Kernel 3b: fold 1/D into G in place: G[b][c][m] *= DINV[b][m].
// passB then needs NO stat loads: out = sum_m exp2(S'[n,m]) * G'[m,c].
// ---------------------------------------------------------------------------
__global__ __launch_bounds__(256) void scale_g_kernel(
    u16* __restrict__ G, const float* __restrict__ DINV){
  const int gid = blockIdx.x*256 + threadIdx.x;
  const int e8 = gid*8;                             // 8 elems per thread
  const int b = e8 / (CCH*NTOK);
  const int rem = e8 - b*CCH*NTOK;
  const int m = rem % NTOK;                         // multiple of 8
  s16x8 g = *(s16x8*)(G + e8);
  const float* d = DINV + (size_t)b*NTOK + m;
  f32x4 d0 = *(const f32x4*)d, d1 = *(const f32x4*)(d+4);
  s16x8 o;
  #pragma unroll
  for(int k=0;k<4;++k){
    o[k]   = (short)f2bf(bf2f((u16)g[k])   * d0[k]);
    o[4+k] = (short)f2bf(bf2f((u16)g[4+k]) * d1[k]);
  }
  *(s16x8*)(G + e8) = o;
}

// ---------------------------------------------------------------------------
// Kernel 4: pass B — LDS-staged deep pipeline. Per 32-m chunk: PH tile
// (32x64 bf16, 4KB) + G' tile (64c x 32m packed 2c/row, 4KB) staged via
// global_load_lds (2 ops/wave), 4-buffer ring, stage-ahead-2, vmcnt(4),
// one s_barrier per chunk. All 4 waves share the staged tiles.
// S' = mfma(PH_frag, theta_frag) -> P = exp2(S') lands in PV A-frag order;
// G' B-frag read with the matching m-permutation.
// ---------------------------------------------------------------------------
template<int MSPLIT>
__global__ __launch_bounds__(256, 4) void passB_kernel(
    const u16* __restrict__ TH, const u16* __restrict__ PH,
    const u16* __restrict__ G, float* __restrict__ OUTP){
  __shared__ __align__(16) u16 ldsPH[4*2048];      // 4 bufs x 4KB
  __shared__ __align__(16) u16 ldsG [4*2048];
  const int bid = blockIdx.x;
  const int xcd = bid & 7, b = xcd >> 1;
  const int j = ((bid >> 3) << 1) | (xcd & 1);     // [0, 36*MSPLIT)
  const int mpart = j % MSPLIT;
  const int nt = j / MSPLIT;                        // [0, 36)
  const int lane = threadIdx.x & 63;
  const int wq = __builtin_amdgcn_readfirstlane((int)(threadIdx.x >> 6));
  const int l15 = lane & 15, lg = lane >> 4;
  const int nbase = nt*128 + wq*32;
  const u16* thb = TH + (size_t)b*NTOK*CCH;
  const u16* phb = PH + (size_t)b*NTOK*CCH;
  const u16* gbb = G  + (size_t)b*CCH*NTOK;
  // hoisted theta B-frags for the wave's 2 n-tiles
  const u16* t0 = thb + (size_t)(nbase + l15)*CCH + lg*8;
  const u16* t1 = t0 + 16*CCH;
  s16x8 bt00 = *(const s16x8*)t0, bt01 = *(const s16x8*)(t0+32);
  s16x8 bt10 = *(const s16x8*)t1, bt11 = *(const s16x8*)(t1+32);
  f32x4 acc[2][4];
  #pragma unroll
  for(int n2=0;n2<2;++n2)
    #pragma unroll
    for(int ct=0;ct<4;++ct) acc[n2][ct] = (f32x4){0.f,0.f,0.f,0.f};

  const int mcnt = NTOK/MSPLIT;
  const int NCH = mcnt/32;
  const int m0 = mpart*mcnt;

  // staging lane-invariants
  const int srl = wq*8 + (lane>>3);                 // local row staged by lane
  const int ssl = (lane&7) ^ (srl&7);               // pre-swizzled slot
  const int gc  = 2*srl + (ssl>>2);                 // G: source channel
  auto STAGE = [&](int ci, int bi){
    const int mc = m0 + ci*32;
    gload16(phb + (size_t)(mc + srl)*CCH + ssl*8, ldsPH + bi*2048 + wq*512);
    gload16(gbb + (size_t)gc*NTOK + mc + (ssl&3)*8, ldsG + bi*2048 + wq*512);
  };

  STAGE(0, 0); STAGE(1, 1);
  #pragma unroll 1
  for(int t=0; t<NCH; ++t){
    int ci = t+2; if(ci >= NCH) ci -= NCH;          // dummy wrap
    STAGE(ci, (t+2)&3);
    WAITVM(4);
    __builtin_amdgcn_s_barrier();
    const u16* bPH = ldsPH + (t&3)*2048;
    const u16* bG  = ldsG  + (t&3)*2048;
    // A-frags (PH rows, XOR-unswizzled)
    s16x8 ap[2][2];
    #pragma unroll
    for(int s=0;s<2;++s){
      const int r = s*16 + l15, rx = r & 7;
      const u16* rb = bPH + r*64;
      ap[s][0] = *(const s16x8*)(rb + ((lg     ^ rx)<<3));
      ap[s][1] = *(const s16x8*)(rb + (((lg+4) ^ rx)<<3));
    }
    // S' (transposed): lane holds S[n=l15][m = ms*16 + 4*lg + r]
    f32x4 sf[2][2];
    #pragma unroll
    for(int n2=0;n2<2;++n2){
      #pragma unroll
      for(int ms=0;ms<2;++ms){
        f32x4 z = {0.f,0.f,0.f,0.f};
        z = mfma16(ap[ms][0], (n2==0)?bt00:bt10, z);
        z = mfma16(ap[ms][1], (n2==0)?bt01:bt11, z);
        sf[n2][ms] = z;
      }
    }
    // G' frags (issue LDS reads before the exp VALU burst)
    s16x4 glo[4], ghi[4];
    #pragma unroll
    for(int ct=0;ct<4;++ct){
      const int c = ct*16 + l15, r = c>>1, rx = r & 7;
      const int lb0 = (c&1)*64 + lg*8, lb1 = lb0 + 32;
      const char* rb = (const char*)bG + r*128;
      glo[ct] = *(const s16x4*)(rb + (((lb0>>4) ^ rx)<<4) + (lb0&15));
      ghi[ct] = *(const s16x4*)(rb + (((lb1>>4) ^ rx)<<4) + (lb1&15));
    }
    // P = exp2(S') packed into PV A-frag (k-slot permutation matches G reads)
    s16x8 pa[2];
    #pragma unroll
    for(int n2=0;n2<2;++n2)
      #pragma unroll
      for(int r=0;r<4;++r){
        pa[n2][r]   = (short)f2bf(exp2f(sf[n2][0][r]));
        pa[n2][4+r] = (short)f2bf(exp2f(sf[n2][1][r]));
      }
    // PV
    #pragma unroll
    for(int ct=0;ct<4;++ct){
      GU gf; gf.p.lo = glo[ct]; gf.p.hi = ghi[ct];
      acc[0][ct] = mfma16(pa[0], gf.v, acc[0][ct]);
      acc[1][ct] = mfma16(pa[1], gf.v, acc[1][ct]);
    }
  }

  float* outp = OUTP + ((size_t)(mpart*NB + b)*NTOK)*CCH;
  #pragma unroll
  for(int n2=0;n2<2;++n2)
    #pragma unroll
    for(int ct=0;ct<4;++ct)
      #pragma unroll
      for(int r=0;r<4;++r)
        outp[(size_t)(nbase + n2*16 + lg*4 + r)*CCH + ct*16 + l15] = acc[n2][ct][r];
}

// ---------------------------------------------------------------------------
// Kernel 5: sum m-partials, apply w_mask 1x1 conv, add x.
// ---------------------------------------------------------------------------
template<int MSPLIT>
__global__ __launch_bounds__(256) void finalize_kernel(
    const float* __restrict__ OUTP, const float* __restrict__ w_mask,
    const float* __restrict__ x, float* __restrict__ out){
  const int b = blockIdx.y;
  const int n = blockIdx.x*64 + (threadIdx.x & 63);
  const int q = __builtin_amdgcn_readfirstlane((int)(threadIdx.x >> 6));
  float v[64];
  #pragma unroll
  for(int c=0;c<64;++c) v[c] = 0.f;
  #pragma unroll
  for(int h=0; h<MSPLIT; ++h){
    const f32x4* r = (const f32x4*)(OUTP + ((size_t)(h*NB + b)*NTOK + n)*CCH);
    #pragma unroll
    for(int t=0;t<16;++t){
      f32x4 u = r[t];
      v[4*t]+=u[0]; v[4*t+1]+=u[1]; v[4*t+2]+=u[2]; v[4*t+3]+=u[3];
    }
  }
  const float* wm = w_mask + q*16*32;   // wave-uniform -> s_loads
  #pragma unroll
  for(int jj=0;jj<16;++jj){
    float a0 = 0.f, a1 = 0.f;
    #pragma unroll
    for(int ic=0;ic<32;++ic){
      float w = wm[jj*32 + ic];
      a0 = fmaf(w, v[2*ic],   a0);
      a1 = fmaf(w, v[2*ic+1], a1);
    }
    const size_t idx = ((size_t)b*CCH + q*16 + jj)*HWSZ + n;
    out[idx]        = a0 + x[idx];
    out[idx + NTOK] = a1 + x[idx + NTOK];
  }
}

// ---------------------------------------------------------------------------
extern "C" void kernel_launch(void* const* d_in, const int* in_sizes, int n_in,
                              void* d_out, int out_size, void* d_ws, size_t ws_size,
                              hipStream_t stream){
  const float* x       = (const float*)d_in[0];
  const float* y       = (const float*)d_in[1];
  const float* w_phi   = (const float*)d_in[2];
  const float* w_theta = (const float*)d_in[3];
  const float* w_g     = (const float*)d_in[4];
  const float* w_mask  = (const float*)d_in[5];
  float* out = (float*)d_out;
  char* ws = (char*)d_ws;

  const size_t projB  = (size_t)NB*NTOK*CCH*sizeof(u16);    // 2,359,296
  const size_t outpB1 = (size_t)NB*NTOK*CCH*sizeof(float);  // 4,718,592 per split
  const size_t fstat  = (size_t)NB*NTOK*sizeof(float);      // 73,728
  const size_t fixed  = 3*projB + (size_t)NSPL*fstat + fstat;

  int msplit = (ws_size >= fixed + 8*outpB1) ? 8
             : (ws_size >= fixed + 4*outpB1) ? 4 : 2;

  size_t off = 0;
  u16*   TH    = (u16*)(ws + off); off += projB;
  u16*   PH    = (u16*)(ws + off); off += projB;
  u16*   G     = (u16*)(ws + off); off += projB;
  float* OUTP  = (float*)(ws + off); off += (size_t)msplit*outpB1;
  float* CSUMP = (float*)(ws + off); off += (size_t)NSPL*fstat;
  float* DINV  = (float*)(ws + off); off += fstat;

  proj_kernel<<<dim3(NTOK/64, NB), 512, 0, stream>>>(x, y, w_phi, w_theta, w_g,
                                                     TH, PH, G);
  passA_kernel<<<dim3((NTOK/128)*NSPL*NB), 256, 0, stream>>>(TH, PH, CSUMP);
  merge_stats_kernel<<<dim3((NB*NTOK)/256), 256, 0, stream>>>(CSUMP, DINV);
  scale_g_kernel<<<dim3((NB*CCH*NTOK)/(256*8)), 256, 0, stream>>>(G, DINV);
  const int gB = (NTOK/128)*msplit*NB;
  switch(msplit){
    case 8: passB_kernel<8><<<dim3(gB),256,0,stream>>>(TH,PH,G,OUTP); break;
    case 4: passB_kernel<4><<<dim3(gB),256,0,stream>>>(TH,PH,G,OUTP); break;
    default: passB_kernel<2><<<dim3(gB),256,0,stream>>>(TH,PH,G,OUTP); break;
  }
  switch(msplit){
    case 8: finalize_kernel<8><<<dim3(NTOK/64,NB),256,0,stream>>>(OUTP,w_mask,x,out); break;
    case 4: finalize_kernel<4><<<dim3(NTOK/64,NB),256,0,stream>>>(OUTP,w_mask,x,out); break;
    default: finalize_kernel<2><<<dim3(NTOK/64,NB),256,0,stream>>>(OUTP,w_mask,x,out); break;
  }
}

// Round 6
// 141.817 us; speedup vs baseline: 1.8851x; 1.0290x over previous
//
#include <hip/hip_runtime.h>

#define NTOK 4608   // token axis N = H*W/2
#define CCH  64     // feature axis C
#define HWSZ 9216   // H*W
#define NB   4      // batch
#define NSPL 8      // passA n-split
#define NCHT (NTOK/32)   // 144 chunks of 32 m
#define L2E  1.4426950408889634f

typedef unsigned short u16;
typedef __attribute__((ext_vector_type(4))) short s16x4;   // 4 bf16
typedef __attribute__((ext_vector_type(8))) short s16x8;   // 8 bf16
typedef __attribute__((ext_vector_type(4))) float f32x4;

__device__ __forceinline__ f32x4 mfma16(s16x8 a, s16x8 b, f32x4 c){
  return __builtin_amdgcn_mfma_f32_16x16x32_bf16(a, b, c, 0, 0, 0);
}
// HW bf16 convert (RNE via v_cvt_pk_bf16_f32; m240: scalar casts fuse)
__device__ __forceinline__ short f2bfh(float f){
  __bf16 h = (__bf16)f;
  return (short)__builtin_bit_cast(unsigned short, h);
}
__device__ __forceinline__ float bf2f(u16 h){
  return __uint_as_float(((unsigned int)h) << 16);
}

// global -> LDS direct copy, 16B per lane (dest = base + lane*16, linear).
__device__ __forceinline__ void gload16(const void* g, void* l){
  __builtin_amdgcn_global_load_lds(
      (const __attribute__((address_space(1))) void*)g,
      (__attribute__((address_space(3))) void*)l, 16, 0, 0);
}
#define SBAR() __builtin_amdgcn_sched_barrier(0)
#define WAITVM(N) do{ SBAR(); asm volatile("s_waitcnt vmcnt(" #N ")" ::: "memory"); SBAR(); }while(0)

// ---------------------------------------------------------------------------
// Kernel 1: fused theta/phi/g projections. theta pre-scaled by log2(e).
// TH/PH[b][pos][c] bf16; G[b][c][m] bf16.
// ---------------------------------------------------------------------------
__global__ __launch_bounds__(512) void proj_kernel(
    const float* __restrict__ x, const float* __restrict__ y,
    const float* __restrict__ w_phi, const float* __restrict__ w_theta,
    const float* __restrict__ w_g,
    u16* __restrict__ TH, u16* __restrict__ PH, u16* __restrict__ G){
  const int b = blockIdx.y;
  const int n = blockIdx.x*64 + (threadIdx.x & 63);
  const int wq = __builtin_amdgcn_readfirstlane((int)(threadIdx.x >> 6)); // 0..7
  const float* xb = x + (size_t)b*CCH*HWSZ;
  const float* yb = y + (size_t)b*CCH*HWSZ;
  const float* wp = w_phi   + wq*4*CCH;
  const float* wt = w_theta + wq*4*CCH;
  const float* wg = w_g     + wq*4*CCH;
  float accP[8], accT[8], accG[8];
  #pragma unroll
  for(int j=0;j<8;++j){ accP[j]=0.f; accT[j]=0.f; accG[j]=0.f; }
  for(int k=0;k<CCH;k+=4){
    float xv0[4], xv1[4], yv0[4], yv1[4];
    #pragma unroll
    for(int u=0;u<4;++u){
      xv0[u] = xb[(size_t)(k+u)*HWSZ + n];
      xv1[u] = xb[(size_t)(k+u)*HWSZ + NTOK + n];
      yv0[u] = yb[(size_t)(k+u)*HWSZ + n];
      yv1[u] = yb[(size_t)(k+u)*HWSZ + NTOK + n];
    }
    #pragma unroll
    for(int u=0;u<4;++u)
      #pragma unroll
      for(int j=0;j<8;++j){
        float xv = (j&1)?xv1[u]:xv0[u];
        accP[j] = fmaf(wp[(j>>1)*CCH + k+u], xv, accP[j]);
        accT[j] = fmaf(wt[(j>>1)*CCH + k+u], (j&1)?yv1[u]:yv0[u], accT[j]);
        accG[j] = fmaf(wg[(j>>1)*CCH + k+u], xv, accG[j]);
      }
  }
  s16x8 vp, vt;
  #pragma unroll
  for(int j=0;j<8;++j){
    vp[j]=f2bfh(accP[j]);
    vt[j]=f2bfh(accT[j]*L2E);          // exp2-domain pre-scale
  }
  *(s16x8*)(PH + ((size_t)b*NTOK + n)*CCH + wq*8) = vp;
  *(s16x8*)(TH + ((size_t)b*NTOK + n)*CCH + wq*8) = vt;
  #pragma unroll
  for(int j=0;j<8;++j)
    G[((size_t)b*CCH + wq*8 + j)*NTOK + n] = f2bfh(accG[j]);
}

// ---------------------------------------------------------------------------
// Kernel 2: pass A — per-column sum of exp2(S'). TH chunks staged via LDS
// ring (4 bufs), stage-ahead-2, counted vmcnt(2), XOR-swizzled b128 reads.
// ---------------------------------------------------------------------------
__global__ __launch_bounds__(256, 4) void passA_kernel(
    const u16* __restrict__ TH, const u16* __restrict__ PH,
    float* __restrict__ CSUMP){
  __shared__ __align__(16) u16 ldsTH[4*2048];
  const int bid = blockIdx.x;
  const int xcd = bid & 7, b = xcd >> 1;
  const int j = ((bid >> 3) << 1) | (xcd & 1);    // [0, 36*NSPL)
  const int part = j & (NSPL-1);
  const int mt = j >> 3;                           // NSPL == 8
  const int lane = threadIdx.x & 63;
  const int wq = __builtin_amdgcn_readfirstlane((int)(threadIdx.x >> 6));
  const int l15 = lane & 15, lg = lane >> 4;
  const int mbase = mt*128 + wq*32;
  const u16* thb = TH + (size_t)b*NTOK*CCH;
  const u16* phb = PH + (size_t)b*NTOK*CCH;
  const u16* p0 = phb + (size_t)(mbase + l15)*CCH + lg*8;
  const u16* p1 = p0 + 16*CCH;
  s16x8 bf00 = *(const s16x8*)p0, bf01 = *(const s16x8*)(p0+32);
  s16x8 bf10 = *(const s16x8*)p1, bf11 = *(const s16x8*)(p1+32);
  float rs0 = 0.f, rs1 = 0.f;

  const int NCH = (NTOK/NSPL)/32;                  // 18
  const int n0 = part*(NTOK/NSPL);
  const int srl = wq*8 + (lane>>3);
  const int ssl = (lane&7) ^ (srl&7);
  auto STAGE = [&](int ci, int bi){
    const u16* src = thb + (size_t)(n0 + ci*32 + srl)*CCH + ssl*8;
    gload16(src, ldsTH + bi*2048 + wq*512);
  };

  STAGE(0, 0); SBAR();
  STAGE(1, 1); SBAR();
  #pragma unroll 1
  for(int t=0; t<NCH; ++t){
    int ci = t+2; if(ci >= NCH) ci -= NCH;
    STAGE(ci, (t+2)&3);
    WAITVM(2);
    __builtin_amdgcn_s_barrier();
    const u16* bTH = ldsTH + (t&3)*2048;
    #pragma unroll
    for(int s=0;s<2;++s){
      const int r = s*16 + l15, rx = r & 7;
      const u16* rb = bTH + r*64;
      s16x8 a0 = *(const s16x8*)(rb + ((lg     ^ rx)<<3));
      s16x8 a1 = *(const s16x8*)(rb + (((lg+4) ^ rx)<<3));
      f32x4 v0 = {0.f,0.f,0.f,0.f}, v1 = {0.f,0.f,0.f,0.f};
      v0 = mfma16(a0, bf00, v0); v0 = mfma16(a1, bf01, v0);
      v1 = mfma16(a0, bf10, v1); v1 = mfma16(a1, bf11, v1);
      rs0 += (exp2f(v0[0])+exp2f(v0[1])) + (exp2f(v0[2])+exp2f(v0[3]));
      rs1 += (exp2f(v1[0])+exp2f(v1[1])) + (exp2f(v1[2])+exp2f(v1[3]));
    }
  }

  rs0 += __shfl_xor(rs0, 16); rs0 += __shfl_xor(rs0, 32);
  rs1 += __shfl_xor(rs1, 16); rs1 += __shfl_xor(rs1, 32);
  if(lg == 0){
    float* dst = CSUMP + (size_t)(part*NB + b)*NTOK + mbase;
    dst[l15]      = rs0;
    dst[16 + l15] = rs1;
  }
}

// ---------------------------------------------------------------------------
// Kernel 3: merge NSPL partial sums -> DINV[m] = 1/sum.
// ---------------------------------------------------------------------------
__global__ __launch_bounds__(256) void merge_stats_kernel(
    const float* __restrict__ CSUMP, float* __restrict__ DINV){
  const int i = blockIdx.x*256 + threadIdx.x;
  if(i >= NB*NTOK) return;
  float s = 0.f;
  #pragma unroll
  for(int h=0; h<NSPL; ++h) s += CSUMP[h*NB*NTOK + i];
  DINV[i] = 1.0f / s;
}

// ---------------------------------------------------------------------------
// Kernel 3b: G2[b][ch][lg][c][8] = PV B-fragments, scaled by 1/D.
// Slot order matches P's k-permutation: j<4 -> m=ch*32+4lg+j,
// j>=4 -> m=ch*32+16+4lg+(j-4). One 16B contiguous frag per lane in passB.
// ---------------------------------------------------------------------------
__global__ __launch_bounds__(256) void scale_g_kernel(
    const u16* __restrict__ G, const float* __restrict__ DINV,
    u16* __restrict__ G2){
  const int tid = threadIdx.x;
  const int c  = tid & 63;
  const int lg = tid >> 6;                    // 0..3
  const int ch = blockIdx.x % NCHT;
  const int b  = blockIdx.x / NCHT;
  const int m0 = ch*32;
  const u16* gr = G + ((size_t)b*CCH + c)*NTOK + m0;
  const float* dv = DINV + (size_t)b*NTOK + m0;
  s16x4 lo = *(const s16x4*)(gr + 4*lg);
  s16x4 hi = *(const s16x4*)(gr + 16 + 4*lg);
  f32x4 d0 = *(const f32x4*)(dv + 4*lg);
  f32x4 d1 = *(const f32x4*)(dv + 16 + 4*lg);
  s16x8 o;
  #pragma unroll
  for(int k=0;k<4;++k){
    o[k]   = f2bfh(bf2f((u16)lo[k]) * d0[k]);
    o[4+k] = f2bfh(bf2f((u16)hi[k]) * d1[k]);
  }
  *(s16x8*)(G2 + ((((size_t)b*NCHT + ch)*4 + lg)*CCH + c)*8) = o;
}

// ---------------------------------------------------------------------------
// Kernel 4: pass B — PH staged via LDS ring (ahead-2, vmcnt counted);
// G2 fragments register-loaded per chunk (issued BEFORE STAGE so the
// compiler's auto-wait is vmcnt(1), never draining the PH prefetch);
// P = exp2(S') packed via HW cvt_pk; PV into fp32 acc. No stat loads.
// ---------------------------------------------------------------------------
template<int MSPLIT>
__global__ __launch_bounds__(256, 4) void passB_kernel(
    const u16* __restrict__ TH, const u16* __restrict__ PH,
    const u16* __restrict__ G2, float* __restrict__ OUTP){
  __shared__ __align__(16) u16 ldsPH[4*2048];
  const int bid = blockIdx.x;
  const int xcd = bid & 7, b = xcd >> 1;
  const int j = ((bid >> 3) << 1) | (xcd & 1);    // [0, 36*MSPLIT)
  const int mpart = j % MSPLIT;
  const int nt = j / MSPLIT;                       // [0, 36)
  const int lane = threadIdx.x & 63;
  const int wq = __builtin_amdgcn_readfirstlane((int)(threadIdx.x >> 6));
  const int l15 = lane & 15, lg = lane >> 4;
  const int nbase = nt*128 + wq*32;
  const u16* thb = TH + (size_t)b*NTOK*CCH;
  const u16* phb = PH + (size_t)b*NTOK*CCH;
  const u16* g2b = G2 + (size_t)b*NCHT*4*CCH*8;
  const u16* t0 = thb + (size_t)(nbase + l15)*CCH + lg*8;
  const u16* t1 = t0 + 16*CCH;
  s16x8 bt00 = *(const s16x8*)t0, bt01 = *(const s16x8*)(t0+32);
  s16x8 bt10 = *(const s16x8*)t1, bt11 = *(const s16x8*)(t1+32);
  f32x4 acc[2][4];
  #pragma unroll
  for(int n2=0;n2<2;++n2)
    #pragma unroll
    for(int ct=0;ct<4;++ct) acc[n2][ct] = (f32x4){0.f,0.f,0.f,0.f};

  const int mcnt = NTOK/MSPLIT;
  const int NCH = mcnt/32;
  const int ch0 = (mpart*mcnt)/32;

  const int srl = wq*8 + (lane>>3);
  const int ssl = (lane&7) ^ (srl&7);
  auto STAGE_PH = [&](int ci, int bi){
    gload16(phb + (size_t)((ch0+ci)*32 + srl)*CCH + ssl*8,
            ldsPH + bi*2048 + wq*512);
  };

  STAGE_PH(0, 0); SBAR();
  STAGE_PH(1, 1); SBAR();
  #pragma unroll 1
  for(int t=0; t<NCH; ++t){
    WAITVM(1);
    __builtin_amdgcn_s_barrier();
    // G2 register loads for chunk t (4 x b128, 4x256B dense per wave)
    const u16* gp = g2b + ((size_t)((ch0+t)*4 + lg)*CCH + l15)*8;
    s16x8 g0 = *(const s16x8*)(gp);
    s16x8 g1 = *(const s16x8*)(gp + 128);
    s16x8 g2 = *(const s16x8*)(gp + 256);
    s16x8 g3 = *(const s16x8*)(gp + 384);
    SBAR();                                        // pin G before STAGE
    int c2 = t+2; if(c2 >= NCH) c2 -= NCH;
    STAGE_PH(c2, (t+2)&3);
    SBAR();                                        // pin staging before compute
    // A-frags from LDS (XOR-unswizzled b128)
    const u16* bPH = ldsPH + (t&3)*2048;
    const int rx = l15 & 7;
    const u16* rb0 = bPH + l15*64;
    const u16* rb1 = rb0 + 16*64;
    s16x8 ap00 = *(const s16x8*)(rb0 + ((lg     ^ rx)<<3));
    s16x8 ap01 = *(const s16x8*)(rb0 + (((lg+4) ^ rx)<<3));
    s16x8 ap10 = *(const s16x8*)(rb1 + ((lg     ^ rx)<<3));
    s16x8 ap11 = *(const s16x8*)(rb1 + (((lg+4) ^ rx)<<3));
    // S' (transposed): lane holds S[n=l15][m = ms*16 + 4*lg + r]
    f32x4 s00={0.f,0.f,0.f,0.f}, s01={0.f,0.f,0.f,0.f};
    f32x4 s10={0.f,0.f,0.f,0.f}, s11={0.f,0.f,0.f,0.f};
    s00 = mfma16(ap00, bt00, s00); s00 = mfma16(ap01, bt01, s00);
    s01 = mfma16(ap10, bt00, s01); s01 = mfma16(ap11, bt01, s01);
    s10 = mfma16(ap00, bt10, s10); s10 = mfma16(ap01, bt11, s10);
    s11 = mfma16(ap10, bt10, s11); s11 = mfma16(ap11, bt11, s11);
    // P = exp2(S'), HW-packed to bf16
    s16x8 pa0, pa1;
    #pragma unroll
    for(int r=0;r<4;++r){
      pa0[r]   = f2bfh(exp2f(s00[r]));
      pa0[4+r] = f2bfh(exp2f(s01[r]));
      pa1[r]   = f2bfh(exp2f(s10[r]));
      pa1[4+r] = f2bfh(exp2f(s11[r]));
    }
    // PV (compiler auto-wait here is vmcnt(1): keeps PH(t+2) in flight)
    acc[0][0] = mfma16(pa0, g0, acc[0][0]);
    acc[1][0] = mfma16(pa1, g0, acc[1][0]);
    acc[0][1] = mfma16(pa0, g1, acc[0][1]);
    acc[1][1] = mfma16(pa1, g1, acc[1][1]);
    acc[0][2] = mfma16(pa0, g2, acc[0][2]);
    acc[1][2] = mfma16(pa1, g2, acc[1][2]);
    acc[0][3] = mfma16(pa0, g3, acc[0][3]);
    acc[1][3] = mfma16(pa1, g3, acc[1][3]);
  }

  float* outp = OUTP + ((size_t)(mpart*NB + b)*NTOK)*CCH;
  #pragma unroll
  for(int n2=0;n2<2;++n2)
    #pragma unroll
    for(int ct=0;ct<4;++ct)
      #pragma unroll
      for(int r=0;r<4;++r)
        outp[(size_t)(nbase + n2*16 + lg*4 + r)*CCH + ct*16 + l15] = acc[n2][ct][r];
}

// ---------------------------------------------------------------------------
// Kernel 5: sum m-partials, apply w_mask 1x1 conv, add x.
// ---------------------------------------------------------------------------
template<int MSPLIT>
__global__ __launch_bounds__(256) void finalize_kernel(
    const float* __restrict__ OUTP, const float* __restrict__ w_mask,
    const float* __restrict__ x, float* __restrict__ out){
  const int b = blockIdx.y;
  const int n = blockIdx.x*64 + (threadIdx.x & 63);
  const int q = __builtin_amdgcn_readfirstlane((int)(threadIdx.x >> 6));
  float v[64];
  #pragma unroll
  for(int c=0;c<64;++c) v[c] = 0.f;
  #pragma unroll
  for(int h=0; h<MSPLIT; ++h){
    const f32x4* r = (const f32x4*)(OUTP + ((size_t)(h*NB + b)*NTOK + n)*CCH);
    #pragma unroll
    for(int t=0;t<16;++t){
      f32x4 u = r[t];
      v[4*t]+=u[0]; v[4*t+1]+=u[1]; v[4*t+2]+=u[2]; v[4*t+3]+=u[3];
    }
  }
  const float* wm = w_mask + q*16*32;   // wave-uniform -> s_loads
  #pragma unroll
  for(int jj=0;jj<16;++jj){
    float a0 = 0.f, a1 = 0.f;
    #pragma unroll
    for(int ic=0;ic<32;++ic){
      float w = wm[jj*32 + ic];
      a0 = fmaf(w, v[2*ic],   a0);
      a1 = fmaf(w, v[2*ic+1], a1);
    }
    const size_t idx = ((size_t)b*CCH + q*16 + jj)*HWSZ + n;
    out[idx]        = a0 + x[idx];
    out[idx + NTOK] = a1 + x[idx + NTOK];
  }
}

// ---------------------------------------------------------------------------
extern "C" void kernel_launch(void* const* d_in, const int* in_sizes, int n_in,
                              void* d_out, int out_size, void* d_ws, size_t ws_size,
                              hipStream_t stream){
  const float* x       = (const float*)d_in[0];
  const float* y       = (const float*)d_in[1];
  const float* w_phi   = (const float*)d_in[2];
  const float* w_theta = (const float*)d_in[3];
  const float* w_g     = (const float*)d_in[4];
  const float* w_mask  = (const float*)d_in[5];
  float* out = (float*)d_out;
  char* ws = (char*)d_ws;

  const size_t projB  = (size_t)NB*NTOK*CCH*sizeof(u16);    // 2,359,296
  const size_t outpB1 = (size_t)NB*NTOK*CCH*sizeof(float);  // 4,718,592 per split
  const size_t fstat  = (size_t)NB*NTOK*sizeof(float);      // 73,728
  const size_t fixed  = 4*projB + (size_t)NSPL*fstat + fstat;  // TH,PH,G,G2,stats

  int msplit = (ws_size >= fixed + 8*outpB1) ? 8
             : (ws_size >= fixed + 4*outpB1) ? 4 : 2;

  size_t off = 0;
  u16*   TH    = (u16*)(ws + off); off += projB;
  u16*   PH    = (u16*)(ws + off); off += projB;
  u16*   G     = (u16*)(ws + off); off += projB;
  u16*   G2    = (u16*)(ws + off); off += projB;
  float* OUTP  = (float*)(ws + off); off += (size_t)msplit*outpB1;
  float* CSUMP = (float*)(ws + off); off += (size_t)NSPL*fstat;
  float* DINV  = (float*)(ws + off); off += fstat;

  proj_kernel<<<dim3(NTOK/64, NB), 512, 0, stream>>>(x, y, w_phi, w_theta, w_g,
                                                     TH, PH, G);
  passA_kernel<<<dim3((NTOK/128)*NSPL*NB), 256, 0, stream>>>(TH, PH, CSUMP);
  merge_stats_kernel<<<dim3((NB*NTOK)/256), 256, 0, stream>>>(CSUMP, DINV);
  scale_g_kernel<<<dim3(NB*NCHT), 256, 0, stream>>>(G, DINV, G2);
  const int gB = (NTOK/128)*msplit*NB;
  switch(msplit){
    case 8: passB_kernel<8><<<dim3(gB),256,0,stream>>>(TH,PH,G2,OUTP); break;
    case 4: passB_kernel<4><<<dim3(gB),256,0,stream>>>(TH,PH,G2,OUTP); break;
    default: passB_kernel<2><<<dim3(gB),256,0,stream>>>(TH,PH,G2,OUTP); break;
  }
  switch(msplit){
    case 8: finalize_kernel<8><<<dim3(NTOK/64,NB),256,0,stream>>>(OUTP,w_mask,x,out); break;
    case 4: finalize_kernel<4><<<dim3(NTOK/64,NB),256,0,stream>>>(OUTP,w_mask,x,out); break;
    default: finalize_kernel<2><<<dim3(NTOK/64,NB),256,0,stream>>>(OUTP,w_mask,x,out); break;
  }
}

// Round 7
// 125.158 us; speedup vs baseline: 2.1361x; 1.1331x over previous
//
#include <hip/hip_runtime.h>

#define NTOK 4608   // token axis N = H*W/2
#define CCH  64     // feature axis C
#define HWSZ 9216   // H*W
#define NB   4      // batch
#define NSPL 8      // passA n-split
#define NCHT (NTOK/32)   // 144 chunks of 32 m
#define L2E  1.4426950408889634f

typedef unsigned short u16;
typedef __attribute__((ext_vector_type(4))) short s16x4;   // 4 bf16
typedef __attribute__((ext_vector_type(8))) short s16x8;   // 8 bf16
typedef __attribute__((ext_vector_type(4))) float f32x4;

__device__ __forceinline__ f32x4 mfma16(s16x8 a, s16x8 b, f32x4 c){
  return __builtin_amdgcn_mfma_f32_16x16x32_bf16(a, b, c, 0, 0, 0);
}
// HW bf16 convert (RNE; pairs fuse to v_cvt_pk_bf16_f32)
__device__ __forceinline__ short f2bfh(float f){
  __bf16 h = (__bf16)f;
  return (short)__builtin_bit_cast(unsigned short, h);
}
__device__ __forceinline__ float bf2f(u16 h){
  return __uint_as_float(((unsigned int)h) << 16);
}
// raw v_exp_f32 (2^x). Inputs bounded (|x| < 40) -> no fixup path needed.
__device__ __forceinline__ float ex2(float x){
  return __builtin_amdgcn_exp2f(x);
}

// global -> LDS direct copy, 16B per lane (dest = base + lane*16, linear).
__device__ __forceinline__ void gload16(const void* g, void* l){
  __builtin_amdgcn_global_load_lds(
      (const __attribute__((address_space(1))) void*)g,
      (__attribute__((address_space(3))) void*)l, 16, 0, 0);
}
#define SBAR() __builtin_amdgcn_sched_barrier(0)
#define WAITVM(N) do{ SBAR(); asm volatile("s_waitcnt vmcnt(" #N ")" ::: "memory"); SBAR(); }while(0)
#define PRIO(N) __builtin_amdgcn_s_setprio(N)

// ---------------------------------------------------------------------------
// Kernel 1: fused theta/phi/g projections. theta pre-scaled by log2(e).
// TH/PH[b][pos][c] bf16; G[b][c][m] bf16.
// ---------------------------------------------------------------------------
__global__ __launch_bounds__(512) void proj_kernel(
    const float* __restrict__ x, const float* __restrict__ y,
    const float* __restrict__ w_phi, const float* __restrict__ w_theta,
    const float* __restrict__ w_g,
    u16* __restrict__ TH, u16* __restrict__ PH, u16* __restrict__ G){
  const int b = blockIdx.y;
  const int n = blockIdx.x*64 + (threadIdx.x & 63);
  const int wq = __builtin_amdgcn_readfirstlane((int)(threadIdx.x >> 6)); // 0..7
  const float* xb = x + (size_t)b*CCH*HWSZ;
  const float* yb = y + (size_t)b*CCH*HWSZ;
  const float* wp = w_phi   + wq*4*CCH;
  const float* wt = w_theta + wq*4*CCH;
  const float* wg = w_g     + wq*4*CCH;
  float accP[8], accT[8], accG[8];
  #pragma unroll
  for(int j=0;j<8;++j){ accP[j]=0.f; accT[j]=0.f; accG[j]=0.f; }
  for(int k=0;k<CCH;k+=4){
    float xv0[4], xv1[4], yv0[4], yv1[4];
    #pragma unroll
    for(int u=0;u<4;++u){
      xv0[u] = xb[(size_t)(k+u)*HWSZ + n];
      xv1[u] = xb[(size_t)(k+u)*HWSZ + NTOK + n];
      yv0[u] = yb[(size_t)(k+u)*HWSZ + n];
      yv1[u] = yb[(size_t)(k+u)*HWSZ + NTOK + n];
    }
    #pragma unroll
    for(int u=0;u<4;++u)
      #pragma unroll
      for(int j=0;j<8;++j){
        float xv = (j&1)?xv1[u]:xv0[u];
        accP[j] = fmaf(wp[(j>>1)*CCH + k+u], xv, accP[j]);
        accT[j] = fmaf(wt[(j>>1)*CCH + k+u], (j&1)?yv1[u]:yv0[u], accT[j]);
        accG[j] = fmaf(wg[(j>>1)*CCH + k+u], xv, accG[j]);
      }
  }
  s16x8 vp, vt;
  #pragma unroll
  for(int j=0;j<8;++j){
    vp[j]=f2bfh(accP[j]);
    vt[j]=f2bfh(accT[j]*L2E);          // exp2-domain pre-scale
  }
  *(s16x8*)(PH + ((size_t)b*NTOK + n)*CCH + wq*8) = vp;
  *(s16x8*)(TH + ((size_t)b*NTOK + n)*CCH + wq*8) = vt;
  #pragma unroll
  for(int j=0;j<8;++j)
    G[((size_t)b*CCH + wq*8 + j)*NTOK + n] = f2bfh(accG[j]);
}

// ---------------------------------------------------------------------------
// Kernel 2: pass A — per-column sum of exp2(S'). TH chunks staged via LDS
// ring (4 bufs), stage-ahead-2, counted vmcnt(2), XOR-swizzled b128 reads.
// ---------------------------------------------------------------------------
__global__ __launch_bounds__(256, 4) void passA_kernel(
    const u16* __restrict__ TH, const u16* __restrict__ PH,
    float* __restrict__ CSUMP){
  __shared__ __align__(16) u16 ldsTH[4*2048];
  const int bid = blockIdx.x;
  const int xcd = bid & 7, b = xcd >> 1;
  const int j = ((bid >> 3) << 1) | (xcd & 1);    // [0, 36*NSPL)
  const int part = j & (NSPL-1);
  const int mt = j >> 3;                           // NSPL == 8
  const int lane = threadIdx.x & 63;
  const int wq = __builtin_amdgcn_readfirstlane((int)(threadIdx.x >> 6));
  const int l15 = lane & 15, lg = lane >> 4;
  const int mbase = mt*128 + wq*32;
  const u16* thb = TH + (size_t)b*NTOK*CCH;
  const u16* phb = PH + (size_t)b*NTOK*CCH;
  const u16* p0 = phb + (size_t)(mbase + l15)*CCH + lg*8;
  const u16* p1 = p0 + 16*CCH;
  s16x8 bf00 = *(const s16x8*)p0, bf01 = *(const s16x8*)(p0+32);
  s16x8 bf10 = *(const s16x8*)p1, bf11 = *(const s16x8*)(p1+32);
  float rs0 = 0.f, rs1 = 0.f;

  const int NCH = (NTOK/NSPL)/32;                  // 18
  const int n0 = part*(NTOK/NSPL);
  const int srl = wq*8 + (lane>>3);
  const int ssl = (lane&7) ^ (srl&7);
  auto STAGE = [&](int ci, int bi){
    const u16* src = thb + (size_t)(n0 + ci*32 + srl)*CCH + ssl*8;
    gload16(src, ldsTH + bi*2048 + wq*512);
  };

  STAGE(0, 0); SBAR();
  STAGE(1, 1); SBAR();
  #pragma unroll 1
  for(int t=0; t<NCH; ++t){
    int ci = t+2; if(ci >= NCH) ci -= NCH;
    STAGE(ci, (t+2)&3);
    WAITVM(2);
    __builtin_amdgcn_s_barrier();
    const u16* bTH = ldsTH + (t&3)*2048;
    #pragma unroll
    for(int s=0;s<2;++s){
      const int r = s*16 + l15, rx = r & 7;
      const u16* rb = bTH + r*64;
      s16x8 a0 = *(const s16x8*)(rb + ((lg     ^ rx)<<3));
      s16x8 a1 = *(const s16x8*)(rb + (((lg+4) ^ rx)<<3));
      f32x4 v0 = {0.f,0.f,0.f,0.f}, v1 = {0.f,0.f,0.f,0.f};
      PRIO(1);
      v0 = mfma16(a0, bf00, v0); v0 = mfma16(a1, bf01, v0);
      v1 = mfma16(a0, bf10, v1); v1 = mfma16(a1, bf11, v1);
      PRIO(0);
      rs0 += (ex2(v0[0])+ex2(v0[1])) + (ex2(v0[2])+ex2(v0[3]));
      rs1 += (ex2(v1[0])+ex2(v1[1])) + (ex2(v1[2])+ex2(v1[3]));
    }
  }

  rs0 += __shfl_xor(rs0, 16); rs0 += __shfl_xor(rs0, 32);
  rs1 += __shfl_xor(rs1, 16); rs1 += __shfl_xor(rs1, 32);
  if(lg == 0){
    float* dst = CSUMP + (size_t)(part*NB + b)*NTOK + mbase;
    dst[l15]      = rs0;
    dst[16 + l15] = rs1;
  }
}

// ---------------------------------------------------------------------------
// Kernel 3: fused stat-merge + G scaling. Block owns one (b, 32-m chunk):
// reduce NSPL partial sums -> 1/D in LDS, then emit G2[b][ch][lg][c][8]
// PV B-fragments scaled by 1/D (slot order matches P's k-permutation).
// ---------------------------------------------------------------------------
__global__ __launch_bounds__(256) void scale_g_kernel(
    const u16* __restrict__ G, const float* __restrict__ CSUMP,
    u16* __restrict__ G2){
  __shared__ float dinv[32];
  const int tid = threadIdx.x;
  const int ch = blockIdx.x % NCHT;
  const int b  = blockIdx.x / NCHT;
  const int m0 = ch*32;
  if(tid < 32){
    float s = 0.f;
    #pragma unroll
    for(int h=0;h<NSPL;++h) s += CSUMP[(size_t)(h*NB+b)*NTOK + m0 + tid];
    dinv[tid] = 1.0f/s;
  }
  __syncthreads();
  const int c  = tid & 63;
  const int lg = tid >> 6;                    // 0..3
  const u16* gr = G + ((size_t)b*CCH + c)*NTOK + m0;
  s16x4 lo = *(const s16x4*)(gr + 4*lg);
  s16x4 hi = *(const s16x4*)(gr + 16 + 4*lg);
  s16x8 o;
  #pragma unroll
  for(int k=0;k<4;++k){
    o[k]   = f2bfh(bf2f((u16)lo[k]) * dinv[4*lg+k]);
    o[4+k] = f2bfh(bf2f((u16)hi[k]) * dinv[16+4*lg+k]);
  }
  *(s16x8*)(G2 + ((((size_t)b*NCHT + ch)*4 + lg)*CCH + c)*8) = o;
}

// ---------------------------------------------------------------------------
// Kernel 4: pass B — PH staged via LDS ring (ahead-2, vmcnt counted);
// G2 fragments register-loaded per chunk; P = exp2(S') via raw v_exp_f32;
// PV into fp32 acc. No stat loads in the loop.
// ---------------------------------------------------------------------------
template<int MSPLIT>
__global__ __launch_bounds__(256, 4) void passB_kernel(
    const u16* __restrict__ TH, const u16* __restrict__ PH,
    const u16* __restrict__ G2, float* __restrict__ OUTP){
  __shared__ __align__(16) u16 ldsPH[4*2048];
  const int bid = blockIdx.x;
  const int xcd = bid & 7, b = xcd >> 1;
  const int j = ((bid >> 3) << 1) | (xcd & 1);    // [0, 36*MSPLIT)
  const int mpart = j % MSPLIT;
  const int nt = j / MSPLIT;                       // [0, 36)
  const int lane = threadIdx.x & 63;
  const int wq = __builtin_amdgcn_readfirstlane((int)(threadIdx.x >> 6));
  const int l15 = lane & 15, lg = lane >> 4;
  const int nbase = nt*128 + wq*32;
  const u16* thb = TH + (size_t)b*NTOK*CCH;
  const u16* phb = PH + (size_t)b*NTOK*CCH;
  const u16* g2b = G2 + (size_t)b*NCHT*4*CCH*8;
  const u16* t0 = thb + (size_t)(nbase + l15)*CCH + lg*8;
  const u16* t1 = t0 + 16*CCH;
  s16x8 bt00 = *(const s16x8*)t0, bt01 = *(const s16x8*)(t0+32);
  s16x8 bt10 = *(const s16x8*)t1, bt11 = *(const s16x8*)(t1+32);
  f32x4 acc[2][4];
  #pragma unroll
  for(int n2=0;n2<2;++n2)
    #pragma unroll
    for(int ct=0;ct<4;++ct) acc[n2][ct] = (f32x4){0.f,0.f,0.f,0.f};

  const int mcnt = NTOK/MSPLIT;
  const int NCH = mcnt/32;
  const int ch0 = (mpart*mcnt)/32;

  const int srl = wq*8 + (lane>>3);
  const int ssl = (lane&7) ^ (srl&7);
  auto STAGE_PH = [&](int ci, int bi){
    gload16(phb + (size_t)((ch0+ci)*32 + srl)*CCH + ssl*8,
            ldsPH + bi*2048 + wq*512);
  };

  STAGE_PH(0, 0); SBAR();
  STAGE_PH(1, 1); SBAR();
  #pragma unroll 1
  for(int t=0; t<NCH; ++t){
    WAITVM(1);
    __builtin_amdgcn_s_barrier();
    // G2 register loads for chunk t (4 x b128, 4x256B dense per wave)
    const u16* gp = g2b + ((size_t)((ch0+t)*4 + lg)*CCH + l15)*8;
    s16x8 g0 = *(const s16x8*)(gp);
    s16x8 g1 = *(const s16x8*)(gp + 128);
    s16x8 g2 = *(const s16x8*)(gp + 256);
    s16x8 g3 = *(const s16x8*)(gp + 384);
    SBAR();                                        // pin G before STAGE
    int c2 = t+2; if(c2 >= NCH) c2 -= NCH;
    STAGE_PH(c2, (t+2)&3);
    SBAR();                                        // pin staging before compute
    // A-frags from LDS (XOR-unswizzled b128)
    const u16* bPH = ldsPH + (t&3)*2048;
    const int rx = l15 & 7;
    const u16* rb0 = bPH + l15*64;
    const u16* rb1 = rb0 + 16*64;
    s16x8 ap00 = *(const s16x8*)(rb0 + ((lg     ^ rx)<<3));
    s16x8 ap01 = *(const s16x8*)(rb0 + (((lg+4) ^ rx)<<3));
    s16x8 ap10 = *(const s16x8*)(rb1 + ((lg     ^ rx)<<3));
    s16x8 ap11 = *(const s16x8*)(rb1 + (((lg+4) ^ rx)<<3));
    // S' (transposed): lane holds S[n=l15][m = ms*16 + 4*lg + r]
    f32x4 s00={0.f,0.f,0.f,0.f}, s01={0.f,0.f,0.f,0.f};
    f32x4 s10={0.f,0.f,0.f,0.f}, s11={0.f,0.f,0.f,0.f};
    PRIO(1);
    s00 = mfma16(ap00, bt00, s00); s00 = mfma16(ap01, bt01, s00);
    s01 = mfma16(ap10, bt00, s01); s01 = mfma16(ap11, bt01, s01);
    s10 = mfma16(ap00, bt10, s10); s10 = mfma16(ap01, bt11, s10);
    s11 = mfma16(ap10, bt10, s11); s11 = mfma16(ap11, bt11, s11);
    PRIO(0);
    // P = exp2(S') via raw v_exp_f32, packed to bf16 (cvt_pk)
    s16x8 pa0, pa1;
    #pragma unroll
    for(int r=0;r<4;++r){
      pa0[r]   = f2bfh(ex2(s00[r]));
      pa0[4+r] = f2bfh(ex2(s01[r]));
      pa1[r]   = f2bfh(ex2(s10[r]));
      pa1[4+r] = f2bfh(ex2(s11[r]));
    }
    // PV (auto-wait here is vmcnt(1): keeps PH(t+2) in flight)
    PRIO(1);
    acc[0][0] = mfma16(pa0, g0, acc[0][0]);
    acc[1][0] = mfma16(pa1, g0, acc[1][0]);
    acc[0][1] = mfma16(pa0, g1, acc[0][1]);
    acc[1][1] = mfma16(pa1, g1, acc[1][1]);
    acc[0][2] = mfma16(pa0, g2, acc[0][2]);
    acc[1][2] = mfma16(pa1, g2, acc[1][2]);
    acc[0][3] = mfma16(pa0, g3, acc[0][3]);
    acc[1][3] = mfma16(pa1, g3, acc[1][3]);
    PRIO(0);
  }

  float* outp = OUTP + ((size_t)(mpart*NB + b)*NTOK)*CCH;
  #pragma unroll
  for(int n2=0;n2<2;++n2)
    #pragma unroll
    for(int ct=0;ct<4;++ct)
      #pragma unroll
      for(int r=0;r<4;++r)
        outp[(size_t)(nbase + n2*16 + lg*4 + r)*CCH + ct*16 + l15] = acc[n2][ct][r];
}

// ---------------------------------------------------------------------------
// Kernel 5: sum m-partials, apply w_mask 1x1 conv, add x.
// ---------------------------------------------------------------------------
template<int MSPLIT>
__global__ __launch_bounds__(256) void finalize_kernel(
    const float* __restrict__ OUTP, const float* __restrict__ w_mask,
    const float* __restrict__ x, float* __restrict__ out){
  const int b = blockIdx.y;
  const int n = blockIdx.x*64 + (threadIdx.x & 63);
  const int q = __builtin_amdgcn_readfirstlane((int)(threadIdx.x >> 6));
  float v[64];
  #pragma unroll
  for(int c=0;c<64;++c) v[c] = 0.f;
  #pragma unroll
  for(int h=0; h<MSPLIT; ++h){
    const f32x4* r = (const f32x4*)(OUTP + ((size_t)(h*NB + b)*NTOK + n)*CCH);
    #pragma unroll
    for(int t=0;t<16;++t){
      f32x4 u = r[t];
      v[4*t]+=u[0]; v[4*t+1]+=u[1]; v[4*t+2]+=u[2]; v[4*t+3]+=u[3];
    }
  }
  const float* wm = w_mask + q*16*32;   // wave-uniform -> s_loads
  #pragma unroll
  for(int jj=0;jj<16;++jj){
    float a0 = 0.f, a1 = 0.f;
    #pragma unroll
    for(int ic=0;ic<32;++ic){
      float w = wm[jj*32 + ic];
      a0 = fmaf(w, v[2*ic],   a0);
      a1 = fmaf(w, v[2*ic+1], a1);
    }
    const size_t idx = ((size_t)b*CCH + q*16 + jj)*HWSZ + n;
    out[idx]        = a0 + x[idx];
    out[idx + NTOK] = a1 + x[idx + NTOK];
  }
}

// ---------------------------------------------------------------------------
extern "C" void kernel_launch(void* const* d_in, const int* in_sizes, int n_in,
                              void* d_out, int out_size, void* d_ws, size_t ws_size,
                              hipStream_t stream){
  const float* x       = (const float*)d_in[0];
  const float* y       = (const float*)d_in[1];
  const float* w_phi   = (const float*)d_in[2];
  const float* w_theta = (const float*)d_in[3];
  const float* w_g     = (const float*)d_in[4];
  const float* w_mask  = (const float*)d_in[5];
  float* out = (float*)d_out;
  char* ws = (char*)d_ws;

  const size_t projB  = (size_t)NB*NTOK*CCH*sizeof(u16);    // 2,359,296
  const size_t outpB1 = (size_t)NB*NTOK*CCH*sizeof(float);  // 4,718,592 per split
  const size_t fstat  = (size_t)NB*NTOK*sizeof(float);      // 73,728
  const size_t fixed  = 4*projB + (size_t)NSPL*fstat;       // TH,PH,G,G2,stats

  int msplit = (ws_size >= fixed + 8*outpB1) ? 8
             : (ws_size >= fixed + 4*outpB1) ? 4 : 2;

  size_t off = 0;
  u16*   TH    = (u16*)(ws + off); off += projB;
  u16*   PH    = (u16*)(ws + off); off += projB;
  u16*   G     = (u16*)(ws + off); off += projB;
  u16*   G2    = (u16*)(ws + off); off += projB;
  float* OUTP  = (float*)(ws + off); off += (size_t)msplit*outpB1;
  float* CSUMP = (float*)(ws + off); off += (size_t)NSPL*fstat;

  proj_kernel<<<dim3(NTOK/64, NB), 512, 0, stream>>>(x, y, w_phi, w_theta, w_g,
                                                     TH, PH, G);
  passA_kernel<<<dim3((NTOK/128)*NSPL*NB), 256, 0, stream>>>(TH, PH, CSUMP);
  scale_g_kernel<<<dim3(NB*NCHT), 256, 0, stream>>>(G, CSUMP, G2);
  const int gB = (NTOK/128)*msplit*NB;
  switch(msplit){
    case 8: passB_kernel<8><<<dim3(gB),256,0,stream>>>(TH,PH,G2,OUTP); break;
    case 4: passB_kernel<4><<<dim3(gB),256,0,stream>>>(TH,PH,G2,OUTP); break;
    default: passB_kernel<2><<<dim3(gB),256,0,stream>>>(TH,PH,G2,OUTP); break;
  }
  switch(msplit){
    case 8: finalize_kernel<8><<<dim3(NTOK/64,NB),256,0,stream>>>(OUTP,w_mask,x,out); break;
    case 4: finalize_kernel<4><<<dim3(NTOK/64,NB),256,0,stream>>>(OUTP,w_mask,x,out); break;
    default: finalize_kernel<2><<<dim3(NTOK/64,NB),256,0,stream>>>(OUTP,w_mask,x,out); break;
  }
}

// Round 8
// 103.822 us; speedup vs baseline: 2.5750x; 1.2055x over previous
//
#include <hip/hip_runtime.h>

#define NTOK 4608   // token axis N = H*W/2
#define CCH  64     // feature axis C
#define HWSZ 9216   // H*W
#define NB   4      // batch
#define NSPL 8      // passA n-split
#define NCHT (NTOK/32)   // 144 chunks of 32 m
#define L2E  1.4426950408889634f

typedef unsigned short u16;
typedef __attribute__((ext_vector_type(4))) short s16x4;   // 4 bf16
typedef __attribute__((ext_vector_type(8))) short s16x8;   // 8 bf16
typedef __attribute__((ext_vector_type(4))) float f32x4;

__device__ __forceinline__ f32x4 mfma16(s16x8 a, s16x8 b, f32x4 c){
  return __builtin_amdgcn_mfma_f32_16x16x32_bf16(a, b, c, 0, 0, 0);
}
// HW bf16 convert (RNE; pairs fuse to v_cvt_pk_bf16_f32)
__device__ __forceinline__ short f2bfh(float f){
  __bf16 h = (__bf16)f;
  return (short)__builtin_bit_cast(unsigned short, h);
}
__device__ __forceinline__ float bf2f(u16 h){
  return __uint_as_float(((unsigned int)h) << 16);
}
// raw v_exp_f32 (2^x). Inputs bounded (|x| < 40) -> no fixup path needed.
__device__ __forceinline__ float ex2(float x){
  return __builtin_amdgcn_exp2f(x);
}

// global -> LDS direct copy, 16B per lane (dest = base + lane*16, linear).
__device__ __forceinline__ void gload16(const void* g, void* l){
  __builtin_amdgcn_global_load_lds(
      (const __attribute__((address_space(1))) void*)g,
      (__attribute__((address_space(3))) void*)l, 16, 0, 0);
}
#define SBAR() __builtin_amdgcn_sched_barrier(0)
#define WAITVM(N) do{ SBAR(); asm volatile("s_waitcnt vmcnt(" #N ")" ::: "memory"); SBAR(); }while(0)
#define PRIO(N) __builtin_amdgcn_s_setprio(N)

// ---------------------------------------------------------------------------
// Kernel 1: fused theta/phi/g projections. theta pre-scaled by log2(e).
// TH/PH[b][pos][c] bf16; G[b][c][m] bf16.
// ---------------------------------------------------------------------------
__global__ __launch_bounds__(512) void proj_kernel(
    const float* __restrict__ x, const float* __restrict__ y,
    const float* __restrict__ w_phi, const float* __restrict__ w_theta,
    const float* __restrict__ w_g,
    u16* __restrict__ TH, u16* __restrict__ PH, u16* __restrict__ G){
  const int b = blockIdx.y;
  const int n = blockIdx.x*64 + (threadIdx.x & 63);
  const int wq = __builtin_amdgcn_readfirstlane((int)(threadIdx.x >> 6)); // 0..7
  const float* xb = x + (size_t)b*CCH*HWSZ;
  const float* yb = y + (size_t)b*CCH*HWSZ;
  const float* wp = w_phi   + wq*4*CCH;
  const float* wt = w_theta + wq*4*CCH;
  const float* wg = w_g     + wq*4*CCH;
  float accP[8], accT[8], accG[8];
  #pragma unroll
  for(int j=0;j<8;++j){ accP[j]=0.f; accT[j]=0.f; accG[j]=0.f; }
  for(int k=0;k<CCH;k+=4){
    float xv0[4], xv1[4], yv0[4], yv1[4];
    #pragma unroll
    for(int u=0;u<4;++u){
      xv0[u] = xb[(size_t)(k+u)*HWSZ + n];
      xv1[u] = xb[(size_t)(k+u)*HWSZ + NTOK + n];
      yv0[u] = yb[(size_t)(k+u)*HWSZ + n];
      yv1[u] = yb[(size_t)(k+u)*HWSZ + NTOK + n];
    }
    #pragma unroll
    for(int u=0;u<4;++u)
      #pragma unroll
      for(int j=0;j<8;++j){
        float xv = (j&1)?xv1[u]:xv0[u];
        accP[j] = fmaf(wp[(j>>1)*CCH + k+u], xv, accP[j]);
        accT[j] = fmaf(wt[(j>>1)*CCH + k+u], (j&1)?yv1[u]:yv0[u], accT[j]);
        accG[j] = fmaf(wg[(j>>1)*CCH + k+u], xv, accG[j]);
      }
  }
  s16x8 vp, vt;
  #pragma unroll
  for(int j=0;j<8;++j){
    vp[j]=f2bfh(accP[j]);
    vt[j]=f2bfh(accT[j]*L2E);          // exp2-domain pre-scale
  }
  *(s16x8*)(PH + ((size_t)b*NTOK + n)*CCH + wq*8) = vp;
  *(s16x8*)(TH + ((size_t)b*NTOK + n)*CCH + wq*8) = vt;
  #pragma unroll
  for(int j=0;j<8;++j)
    G[((size_t)b*CCH + wq*8 + j)*NTOK + n] = f2bfh(accG[j]);
}

// ---------------------------------------------------------------------------
// Kernel 2: pass A — per-column sum of exp2(S'). TH chunks staged via LDS
// ring (4 bufs), stage-ahead-2, counted vmcnt(2), XOR-swizzled b128 reads.
// ---------------------------------------------------------------------------
__global__ __launch_bounds__(256, 4) void passA_kernel(
    const u16* __restrict__ TH, const u16* __restrict__ PH,
    float* __restrict__ CSUMP){
  __shared__ __align__(16) u16 ldsTH[4*2048];
  const int bid = blockIdx.x;
  const int xcd = bid & 7, b = xcd >> 1;
  const int j = ((bid >> 3) << 1) | (xcd & 1);    // [0, 36*NSPL)
  const int part = j & (NSPL-1);
  const int mt = j >> 3;                           // NSPL == 8
  const int lane = threadIdx.x & 63;
  const int wq = __builtin_amdgcn_readfirstlane((int)(threadIdx.x >> 6));
  const int l15 = lane & 15, lg = lane >> 4;
  const int mbase = mt*128 + wq*32;
  const u16* thb = TH + (size_t)b*NTOK*CCH;
  const u16* phb = PH + (size_t)b*NTOK*CCH;
  const u16* p0 = phb + (size_t)(mbase + l15)*CCH + lg*8;
  const u16* p1 = p0 + 16*CCH;
  s16x8 bf00 = *(const s16x8*)p0, bf01 = *(const s16x8*)(p0+32);
  s16x8 bf10 = *(const s16x8*)p1, bf11 = *(const s16x8*)(p1+32);
  float rs0 = 0.f, rs1 = 0.f;

  const int NCH = (NTOK/NSPL)/32;                  // 18
  const int n0 = part*(NTOK/NSPL);
  const int srl = wq*8 + (lane>>3);
  const int ssl = (lane&7) ^ (srl&7);
  auto STAGE = [&](int ci, int bi){
    const u16* src = thb + (size_t)(n0 + ci*32 + srl)*CCH + ssl*8;
    gload16(src, ldsTH + bi*2048 + wq*512);
  };

  STAGE(0, 0); SBAR();
  STAGE(1, 1); SBAR();
  #pragma unroll 1
  for(int t=0; t<NCH; ++t){
    int ci = t+2; if(ci >= NCH) ci -= NCH;
    STAGE(ci, (t+2)&3);
    WAITVM(2);
    __builtin_amdgcn_s_barrier();
    const u16* bTH = ldsTH + (t&3)*2048;
    #pragma unroll
    for(int s=0;s<2;++s){
      const int r = s*16 + l15, rx = r & 7;
      const u16* rb = bTH + r*64;
      s16x8 a0 = *(const s16x8*)(rb + ((lg     ^ rx)<<3));
      s16x8 a1 = *(const s16x8*)(rb + (((lg+4) ^ rx)<<3));
      f32x4 v0 = {0.f,0.f,0.f,0.f}, v1 = {0.f,0.f,0.f,0.f};
      PRIO(1);
      v0 = mfma16(a0, bf00, v0); v0 = mfma16(a1, bf01, v0);
      v1 = mfma16(a0, bf10, v1); v1 = mfma16(a1, bf11, v1);
      PRIO(0);
      rs0 += (ex2(v0[0])+ex2(v0[1])) + (ex2(v0[2])+ex2(v0[3]));
      rs1 += (ex2(v1[0])+ex2(v1[1])) + (ex2(v1[2])+ex2(v1[3]));
    }
  }

  rs0 += __shfl_xor(rs0, 16); rs0 += __shfl_xor(rs0, 32);
  rs1 += __shfl_xor(rs1, 16); rs1 += __shfl_xor(rs1, 32);
  if(lg == 0){
    float* dst = CSUMP + (size_t)(part*NB + b)*NTOK + mbase;
    dst[l15]      = rs0;
    dst[16 + l15] = rs1;
  }
}

// ---------------------------------------------------------------------------
// Kernel 3: fused stat-merge + G scaling. Block owns one (b, 32-m chunk):
// reduce NSPL partial sums -> 1/D in LDS, then emit G2[b][ch][lg][c][8]
// PV B-fragments scaled by 1/D (slot order matches P's k-permutation).
// ---------------------------------------------------------------------------
__global__ __launch_bounds__(256) void scale_g_kernel(
    const u16* __restrict__ G, const float* __restrict__ CSUMP,
    u16* __restrict__ G2){
  __shared__ float dinv[32];
  const int tid = threadIdx.x;
  const int ch = blockIdx.x % NCHT;
  const int b  = blockIdx.x / NCHT;
  const int m0 = ch*32;
  if(tid < 32){
    float s = 0.f;
    #pragma unroll
    for(int h=0;h<NSPL;++h) s += CSUMP[(size_t)(h*NB+b)*NTOK + m0 + tid];
    dinv[tid] = 1.0f/s;
  }
  __syncthreads();
  const int c  = tid & 63;
  const int lg = tid >> 6;                    // 0..3
  const u16* gr = G + ((size_t)b*CCH + c)*NTOK + m0;
  s16x4 lo = *(const s16x4*)(gr + 4*lg);
  s16x4 hi = *(const s16x4*)(gr + 16 + 4*lg);
  s16x8 o;
  #pragma unroll
  for(int k=0;k<4;++k){
    o[k]   = f2bfh(bf2f((u16)lo[k]) * dinv[4*lg+k]);
    o[4+k] = f2bfh(bf2f((u16)hi[k]) * dinv[16+4*lg+k]);
  }
  *(s16x8*)(G2 + ((((size_t)b*NCHT + ch)*4 + lg)*CCH + c)*8) = o;
}

// ---------------------------------------------------------------------------
// Kernel 4: pass B — PH staged via LDS ring (ahead-2, vmcnt counted);
// G2 fragments register-loaded per chunk; P = exp2(S') via raw v_exp_f32;
// PV into fp32 acc. No stat loads in the loop.
// ---------------------------------------------------------------------------
template<int MSPLIT>
__global__ __launch_bounds__(256, 4) void passB_kernel(
    const u16* __restrict__ TH, const u16* __restrict__ PH,
    const u16* __restrict__ G2, float* __restrict__ OUTP){
  __shared__ __align__(16) u16 ldsPH[4*2048];
  const int bid = blockIdx.x;
  const int xcd = bid & 7, b = xcd >> 1;
  const int j = ((bid >> 3) << 1) | (xcd & 1);    // [0, 36*MSPLIT)
  const int mpart = j % MSPLIT;
  const int nt = j / MSPLIT;                       // [0, 36)
  const int lane = threadIdx.x & 63;
  const int wq = __builtin_amdgcn_readfirstlane((int)(threadIdx.x >> 6));
  const int l15 = lane & 15, lg = lane >> 4;
  const int nbase = nt*128 + wq*32;
  const u16* thb = TH + (size_t)b*NTOK*CCH;
  const u16* phb = PH + (size_t)b*NTOK*CCH;
  const u16* g2b = G2 + (size_t)b*NCHT*4*CCH*8;
  const u16* t0 = thb + (size_t)(nbase + l15)*CCH + lg*8;
  const u16* t1 = t0 + 16*CCH;
  s16x8 bt00 = *(const s16x8*)t0, bt01 = *(const s16x8*)(t0+32);
  s16x8 bt10 = *(const s16x8*)t1, bt11 = *(const s16x8*)(t1+32);
  f32x4 acc[2][4];
  #pragma unroll
  for(int n2=0;n2<2;++n2)
    #pragma unroll
    for(int ct=0;ct<4;++ct) acc[n2][ct] = (f32x4){0.f,0.f,0.f,0.f};

  const int mcnt = NTOK/MSPLIT;
  const int NCH = mcnt/32;
  const int ch0 = (mpart*mcnt)/32;

  const int srl = wq*8 + (lane>>3);
  const int ssl = (lane&7) ^ (srl&7);
  auto STAGE_PH = [&](int ci, int bi){
    gload16(phb + (size_t)((ch0+ci)*32 + srl)*CCH + ssl*8,
            ldsPH + bi*2048 + wq*512);
  };

  STAGE_PH(0, 0); SBAR();
  STAGE_PH(1, 1); SBAR();
  #pragma unroll 1
  for(int t=0; t<NCH; ++t){
    WAITVM(1);
    __builtin_amdgcn_s_barrier();
    // G2 register loads for chunk t (4 x b128, 4x256B dense per wave)
    const u16* gp = g2b + ((size_t)((ch0+t)*4 + lg)*CCH + l15)*8;
    s16x8 g0 = *(const s16x8*)(gp);
    s16x8 g1 = *(const s16x8*)(gp + 128);
    s16x8 g2 = *(const s16x8*)(gp + 256);
    s16x8 g3 = *(const s16x8*)(gp + 384);
    SBAR();                                        // pin G before STAGE
    int c2 = t+2; if(c2 >= NCH) c2 -= NCH;
    STAGE_PH(c2, (t+2)&3);
    SBAR();                                        // pin staging before compute
    // A-frags from LDS (XOR-unswizzled b128)
    const u16* bPH = ldsPH + (t&3)*2048;
    const int rx = l15 & 7;
    const u16* rb0 = bPH + l15*64;
    const u16* rb1 = rb0 + 16*64;
    s16x8 ap00 = *(const s16x8*)(rb0 + ((lg     ^ rx)<<3));
    s16x8 ap01 = *(const s16x8*)(rb0 + (((lg+4) ^ rx)<<3));
    s16x8 ap10 = *(const s16x8*)(rb1 + ((lg     ^ rx)<<3));
    s16x8 ap11 = *(const s16x8*)(rb1 + (((lg+4) ^ rx)<<3));
    // S' (transposed): lane holds S[n=l15][m = ms*16 + 4*lg + r]
    f32x4 s00={0.f,0.f,0.f,0.f}, s01={0.f,0.f,0.f,0.f};
    f32x4 s10={0.f,0.f,0.f,0.f}, s11={0.f,0.f,0.f,0.f};
    PRIO(1);
    s00 = mfma16(ap00, bt00, s00); s00 = mfma16(ap01, bt01, s00);
    s01 = mfma16(ap10, bt00, s01); s01 = mfma16(ap11, bt01, s01);
    s10 = mfma16(ap00, bt10, s10); s10 = mfma16(ap01, bt11, s10);
    s11 = mfma16(ap10, bt10, s11); s11 = mfma16(ap11, bt11, s11);
    PRIO(0);
    // P = exp2(S') via raw v_exp_f32, packed to bf16 (cvt_pk)
    s16x8 pa0, pa1;
    #pragma unroll
    for(int r=0;r<4;++r){
      pa0[r]   = f2bfh(ex2(s00[r]));
      pa0[4+r] = f2bfh(ex2(s01[r]));
      pa1[r]   = f2bfh(ex2(s10[r]));
      pa1[4+r] = f2bfh(ex2(s11[r]));
    }
    // PV (auto-wait here is vmcnt(1): keeps PH(t+2) in flight)
    PRIO(1);
    acc[0][0] = mfma16(pa0, g0, acc[0][0]);
    acc[1][0] = mfma16(pa1, g0, acc[1][0]);
    acc[0][1] = mfma16(pa0, g1, acc[0][1]);
    acc[1][1] = mfma16(pa1, g1, acc[1][1]);
    acc[0][2] = mfma16(pa0, g2, acc[0][2]);
    acc[1][2] = mfma16(pa1, g2, acc[1][2]);
    acc[0][3] = mfma16(pa0, g3, acc[0][3]);
    acc[1][3] = mfma16(pa1, g3, acc[1][3]);
    PRIO(0);
  }

  float* outp = OUTP + ((size_t)(mpart*NB + b)*NTOK)*CCH;
  #pragma unroll
  for(int n2=0;n2<2;++n2)
    #pragma unroll
    for(int ct=0;ct<4;++ct)
      #pragma unroll
      for(int r=0;r<4;++r)
        outp[(size_t)(nbase + n2*16 + lg*4 + r)*CCH + ct*16 + l15] = acc[n2][ct][r];
}

// ---------------------------------------------------------------------------
// Kernel 5a: reduce m-partials. OUTS[i] = sum_h OUTP[h][i]. Pure streaming
// f32x4, fully coalesced, ~32 VGPR, no spill.
// ---------------------------------------------------------------------------
__global__ __launch_bounds__(256) void reduce_kernel(
    const float* __restrict__ OUTP, float* __restrict__ OUTS, int msplit){
  const int gid = blockIdx.x*256 + threadIdx.x;          // f32x4 index
  const size_t stride4 = (size_t)NB*NTOK*CCH/4;
  const f32x4* src = (const f32x4*)OUTP;
  f32x4 a = src[gid];
  for(int h=1; h<msplit; ++h){
    f32x4 u = src[h*stride4 + gid];
    a[0]+=u[0]; a[1]+=u[1]; a[2]+=u[2]; a[3]+=u[3];
  }
  ((f32x4*)OUTS)[gid] = a;
}

// ---------------------------------------------------------------------------
// Kernel 5b: w_mask 1x1 conv + residual. 512 thr = 64 tokens x 8 waves
// (8 output channels each). Per-lane v[16] f32x4 (statically indexed, fits
// registers under __launch_bounds__(512,2)). wm rows via wave-uniform s_loads.
// ---------------------------------------------------------------------------
__global__ __launch_bounds__(512, 2) void conv_kernel(
    const float* __restrict__ OUTS, const float* __restrict__ w_mask,
    const float* __restrict__ x, float* __restrict__ out){
  const int b = blockIdx.y;
  const int nl = threadIdx.x & 63;
  const int n = blockIdx.x*64 + nl;
  const int q = __builtin_amdgcn_readfirstlane((int)(threadIdx.x >> 6)); // 0..7
  const f32x4* vr = (const f32x4*)(OUTS + ((size_t)b*NTOK + n)*CCH);
  f32x4 v[16];
  #pragma unroll
  for(int k=0;k<16;++k) v[k] = vr[k];
  const float* wm = w_mask + q*8*32;       // 8 rows of 32, wave-uniform
  #pragma unroll
  for(int jj=0;jj<8;++jj){
    float a0 = 0.f, a1 = 0.f;
    #pragma unroll
    for(int ic=0;ic<32;++ic){
      float w = wm[jj*32 + ic];
      a0 = fmaf(w, v[ic>>1][(2*ic)&3],   a0);
      a1 = fmaf(w, v[ic>>1][(2*ic+1)&3], a1);
    }
    const size_t idx = ((size_t)b*CCH + q*8 + jj)*HWSZ + n;
    out[idx]        = a0 + x[idx];
    out[idx + NTOK] = a1 + x[idx + NTOK];
  }
}

// ---------------------------------------------------------------------------
extern "C" void kernel_launch(void* const* d_in, const int* in_sizes, int n_in,
                              void* d_out, int out_size, void* d_ws, size_t ws_size,
                              hipStream_t stream){
  const float* x       = (const float*)d_in[0];
  const float* y       = (const float*)d_in[1];
  const float* w_phi   = (const float*)d_in[2];
  const float* w_theta = (const float*)d_in[3];
  const float* w_g     = (const float*)d_in[4];
  const float* w_mask  = (const float*)d_in[5];
  float* out = (float*)d_out;
  char* ws = (char*)d_ws;

  const size_t projB  = (size_t)NB*NTOK*CCH*sizeof(u16);    // 2,359,296
  const size_t outpB1 = (size_t)NB*NTOK*CCH*sizeof(float);  // 4,718,592 per split
  const size_t fstat  = (size_t)NB*NTOK*sizeof(float);      // 73,728
  const size_t fixed  = 4*projB + (size_t)NSPL*fstat + outpB1; // TH,PH,G,G2,stats,OUTS

  int msplit = (ws_size >= fixed + 8*outpB1) ? 8
             : (ws_size >= fixed + 4*outpB1) ? 4 : 2;

  size_t off = 0;
  u16*   TH    = (u16*)(ws + off); off += projB;
  u16*   PH    = (u16*)(ws + off); off += projB;
  u16*   G     = (u16*)(ws + off); off += projB;
  u16*   G2    = (u16*)(ws + off); off += projB;
  float* OUTP  = (float*)(ws + off); off += (size_t)msplit*outpB1;
  float* OUTS  = (float*)(ws + off); off += outpB1;
  float* CSUMP = (float*)(ws + off); off += (size_t)NSPL*fstat;

  proj_kernel<<<dim3(NTOK/64, NB), 512, 0, stream>>>(x, y, w_phi, w_theta, w_g,
                                                     TH, PH, G);
  passA_kernel<<<dim3((NTOK/128)*NSPL*NB), 256, 0, stream>>>(TH, PH, CSUMP);
  scale_g_kernel<<<dim3(NB*NCHT), 256, 0, stream>>>(G, CSUMP, G2);
  const int gB = (NTOK/128)*msplit*NB;
  switch(msplit){
    case 8: passB_kernel<8><<<dim3(gB),256,0,stream>>>(TH,PH,G2,OUTP); break;
    case 4: passB_kernel<4><<<dim3(gB),256,0,stream>>>(TH,PH,G2,OUTP); break;
    default: passB_kernel<2><<<dim3(gB),256,0,stream>>>(TH,PH,G2,OUTP); break;
  }
  reduce_kernel<<<dim3((NB*NTOK*CCH/4)/256), 256, 0, stream>>>(OUTP, OUTS, msplit);
  conv_kernel<<<dim3(NTOK/64, NB), 512, 0, stream>>>(OUTS, w_mask, x, out);
}

// Round 9
// 103.729 us; speedup vs baseline: 2.5773x; 1.0009x over previous
//
#include <hip/hip_runtime.h>

#define NTOK 4608   // token axis N = H*W/2
#define CCH  64     // feature axis C
#define HWSZ 9216   // H*W
#define NB   4      // batch
#define NSPL 8      // passA n-split
#define NCHT (NTOK/32)   // 144 chunks of 32 m
#define L2E  1.4426950408889634f

typedef unsigned short u16;
typedef __attribute__((ext_vector_type(4))) short s16x4;   // 4 bf16
typedef __attribute__((ext_vector_type(8))) short s16x8;   // 8 bf16
typedef __attribute__((ext_vector_type(4))) float f32x4;

__device__ __forceinline__ f32x4 mfma16(s16x8 a, s16x8 b, f32x4 c){
  return __builtin_amdgcn_mfma_f32_16x16x32_bf16(a, b, c, 0, 0, 0);
}
// HW bf16 convert (RNE; pairs fuse to v_cvt_pk_bf16_f32)
__device__ __forceinline__ short f2bfh(float f){
  __bf16 h = (__bf16)f;
  return (short)__builtin_bit_cast(unsigned short, h);
}
__device__ __forceinline__ float bf2f(u16 h){
  return __uint_as_float(((unsigned int)h) << 16);
}
// raw v_exp_f32 (2^x). Inputs bounded (|x| < 40) -> no fixup path needed.
__device__ __forceinline__ float ex2(float x){
  return __builtin_amdgcn_exp2f(x);
}

// global -> LDS direct copy, 16B per lane (dest = base + lane*16, linear).
__device__ __forceinline__ void gload16(const void* g, void* l){
  __builtin_amdgcn_global_load_lds(
      (const __attribute__((address_space(1))) void*)g,
      (__attribute__((address_space(3))) void*)l, 16, 0, 0);
}
#define SBAR() __builtin_amdgcn_sched_barrier(0)
#define WAITVM(N) do{ SBAR(); asm volatile("s_waitcnt vmcnt(" #N ")" ::: "memory"); SBAR(); }while(0)
#define PRIO(N) __builtin_amdgcn_s_setprio(N)

// ---------------------------------------------------------------------------
// Kernel 1: fused theta/phi/g projections. theta pre-scaled by log2(e).
// TH/PH[b][pos][c] bf16; G[b][c][m] bf16.
// ---------------------------------------------------------------------------
__global__ __launch_bounds__(512) void proj_kernel(
    const float* __restrict__ x, const float* __restrict__ y,
    const float* __restrict__ w_phi, const float* __restrict__ w_theta,
    const float* __restrict__ w_g,
    u16* __restrict__ TH, u16* __restrict__ PH, u16* __restrict__ G){
  const int b = blockIdx.y;
  const int n = blockIdx.x*64 + (threadIdx.x & 63);
  const int wq = __builtin_amdgcn_readfirstlane((int)(threadIdx.x >> 6)); // 0..7
  const float* xb = x + (size_t)b*CCH*HWSZ;
  const float* yb = y + (size_t)b*CCH*HWSZ;
  const float* wp = w_phi   + wq*4*CCH;
  const float* wt = w_theta + wq*4*CCH;
  const float* wg = w_g     + wq*4*CCH;
  float accP[8], accT[8], accG[8];
  #pragma unroll
  for(int j=0;j<8;++j){ accP[j]=0.f; accT[j]=0.f; accG[j]=0.f; }
  for(int k=0;k<CCH;k+=4){
    float xv0[4], xv1[4], yv0[4], yv1[4];
    #pragma unroll
    for(int u=0;u<4;++u){
      xv0[u] = xb[(size_t)(k+u)*HWSZ + n];
      xv1[u] = xb[(size_t)(k+u)*HWSZ + NTOK + n];
      yv0[u] = yb[(size_t)(k+u)*HWSZ + n];
      yv1[u] = yb[(size_t)(k+u)*HWSZ + NTOK + n];
    }
    #pragma unroll
    for(int u=0;u<4;++u)
      #pragma unroll
      for(int j=0;j<8;++j){
        float xv = (j&1)?xv1[u]:xv0[u];
        accP[j] = fmaf(wp[(j>>1)*CCH + k+u], xv, accP[j]);
        accT[j] = fmaf(wt[(j>>1)*CCH + k+u], (j&1)?yv1[u]:yv0[u], accT[j]);
        accG[j] = fmaf(wg[(j>>1)*CCH + k+u], xv, accG[j]);
      }
  }
  s16x8 vp, vt;
  #pragma unroll
  for(int j=0;j<8;++j){
    vp[j]=f2bfh(accP[j]);
    vt[j]=f2bfh(accT[j]*L2E);          // exp2-domain pre-scale
  }
  *(s16x8*)(PH + ((size_t)b*NTOK + n)*CCH + wq*8) = vp;
  *(s16x8*)(TH + ((size_t)b*NTOK + n)*CCH + wq*8) = vt;
  #pragma unroll
  for(int j=0;j<8;++j)
    G[((size_t)b*CCH + wq*8 + j)*NTOK + n] = f2bfh(accG[j]);
}

// ---------------------------------------------------------------------------
// Kernel 2: pass A — per-column sum of exp2(S'). TH chunks staged via LDS
// ring (4 bufs), stage-ahead-2, counted vmcnt(2), XOR-swizzled b128 reads.
// ---------------------------------------------------------------------------
__global__ __launch_bounds__(256, 4) void passA_kernel(
    const u16* __restrict__ TH, const u16* __restrict__ PH,
    float* __restrict__ CSUMP){
  __shared__ __align__(16) u16 ldsTH[4*2048];
  const int bid = blockIdx.x;
  const int xcd = bid & 7, b = xcd >> 1;
  const int j = ((bid >> 3) << 1) | (xcd & 1);    // [0, 36*NSPL)
  const int part = j & (NSPL-1);
  const int mt = j >> 3;                           // NSPL == 8
  const int lane = threadIdx.x & 63;
  const int wq = __builtin_amdgcn_readfirstlane((int)(threadIdx.x >> 6));
  const int l15 = lane & 15, lg = lane >> 4;
  const int mbase = mt*128 + wq*32;
  const u16* thb = TH + (size_t)b*NTOK*CCH;
  const u16* phb = PH + (size_t)b*NTOK*CCH;
  const u16* p0 = phb + (size_t)(mbase + l15)*CCH + lg*8;
  const u16* p1 = p0 + 16*CCH;
  s16x8 bf00 = *(const s16x8*)p0, bf01 = *(const s16x8*)(p0+32);
  s16x8 bf10 = *(const s16x8*)p1, bf11 = *(const s16x8*)(p1+32);
  float rs0 = 0.f, rs1 = 0.f;

  const int NCH = (NTOK/NSPL)/32;                  // 18
  const int n0 = part*(NTOK/NSPL);
  const int srl = wq*8 + (lane>>3);
  const int ssl = (lane&7) ^ (srl&7);
  auto STAGE = [&](int ci, int bi){
    const u16* src = thb + (size_t)(n0 + ci*32 + srl)*CCH + ssl*8;
    gload16(src, ldsTH + bi*2048 + wq*512);
  };

  STAGE(0, 0); SBAR();
  STAGE(1, 1); SBAR();
  #pragma unroll 1
  for(int t=0; t<NCH; ++t){
    int ci = t+2; if(ci >= NCH) ci -= NCH;
    STAGE(ci, (t+2)&3);
    WAITVM(2);
    __builtin_amdgcn_s_barrier();
    const u16* bTH = ldsTH + (t&3)*2048;
    #pragma unroll
    for(int s=0;s<2;++s){
      const int r = s*16 + l15, rx = r & 7;
      const u16* rb = bTH + r*64;
      s16x8 a0 = *(const s16x8*)(rb + ((lg     ^ rx)<<3));
      s16x8 a1 = *(const s16x8*)(rb + (((lg+4) ^ rx)<<3));
      f32x4 v0 = {0.f,0.f,0.f,0.f}, v1 = {0.f,0.f,0.f,0.f};
      PRIO(1);
      v0 = mfma16(a0, bf00, v0); v0 = mfma16(a1, bf01, v0);
      v1 = mfma16(a0, bf10, v1); v1 = mfma16(a1, bf11, v1);
      PRIO(0);
      rs0 += (ex2(v0[0])+ex2(v0[1])) + (ex2(v0[2])+ex2(v0[3]));
      rs1 += (ex2(v1[0])+ex2(v1[1])) + (ex2(v1[2])+ex2(v1[3]));
    }
  }

  rs0 += __shfl_xor(rs0, 16); rs0 += __shfl_xor(rs0, 32);
  rs1 += __shfl_xor(rs1, 16); rs1 += __shfl_xor(rs1, 32);
  if(lg == 0){
    float* dst = CSUMP + (size_t)(part*NB + b)*NTOK + mbase;
    dst[l15]      = rs0;
    dst[16 + l15] = rs1;
  }
}

// ---------------------------------------------------------------------------
// Kernel 3: fused stat-merge + G scaling. Block owns one (b, 32-m chunk):
// reduce NSPL partial sums -> 1/D in LDS, then emit G2[b][ch][lg][c][8]
// PV B-fragments scaled by 1/D (slot order matches P's k-permutation).
// ---------------------------------------------------------------------------
__global__ __launch_bounds__(256) void scale_g_kernel(
    const u16* __restrict__ G, const float* __restrict__ CSUMP,
    u16* __restrict__ G2){
  __shared__ float dinv[32];
  const int tid = threadIdx.x;
  const int ch = blockIdx.x % NCHT;
  const int b  = blockIdx.x / NCHT;
  const int m0 = ch*32;
  if(tid < 32){
    float s = 0.f;
    #pragma unroll
    for(int h=0;h<NSPL;++h) s += CSUMP[(size_t)(h*NB+b)*NTOK + m0 + tid];
    dinv[tid] = 1.0f/s;
  }
  __syncthreads();
  const int c  = tid & 63;
  const int lg = tid >> 6;                    // 0..3
  const u16* gr = G + ((size_t)b*CCH + c)*NTOK + m0;
  s16x4 lo = *(const s16x4*)(gr + 4*lg);
  s16x4 hi = *(const s16x4*)(gr + 16 + 4*lg);
  s16x8 o;
  #pragma unroll
  for(int k=0;k<4;++k){
    o[k]   = f2bfh(bf2f((u16)lo[k]) * dinv[4*lg+k]);
    o[4+k] = f2bfh(bf2f((u16)hi[k]) * dinv[16+4*lg+k]);
  }
  *(s16x8*)(G2 + ((((size_t)b*NCHT + ch)*4 + lg)*CCH + c)*8) = o;
}

// ---------------------------------------------------------------------------
// Kernel 4: pass B — PH staged via LDS ring (ahead-2, vmcnt counted);
// G2 fragments register-loaded per chunk; P = exp2(S') via raw v_exp_f32;
// PV into fp32 acc. No stat loads in the loop.
// ---------------------------------------------------------------------------
template<int MSPLIT>
__global__ __launch_bounds__(256, 4) void passB_kernel(
    const u16* __restrict__ TH, const u16* __restrict__ PH,
    const u16* __restrict__ G2, float* __restrict__ OUTP){
  __shared__ __align__(16) u16 ldsPH[4*2048];
  const int bid = blockIdx.x;
  const int xcd = bid & 7, b = xcd >> 1;
  const int j = ((bid >> 3) << 1) | (xcd & 1);    // [0, 36*MSPLIT)
  const int mpart = j % MSPLIT;
  const int nt = j / MSPLIT;                       // [0, 36)
  const int lane = threadIdx.x & 63;
  const int wq = __builtin_amdgcn_readfirstlane((int)(threadIdx.x >> 6));
  const int l15 = lane & 15, lg = lane >> 4;
  const int nbase = nt*128 + wq*32;
  const u16* thb = TH + (size_t)b*NTOK*CCH;
  const u16* phb = PH + (size_t)b*NTOK*CCH;
  const u16* g2b = G2 + (size_t)b*NCHT*4*CCH*8;
  const u16* t0 = thb + (size_t)(nbase + l15)*CCH + lg*8;
  const u16* t1 = t0 + 16*CCH;
  s16x8 bt00 = *(const s16x8*)t0, bt01 = *(const s16x8*)(t0+32);
  s16x8 bt10 = *(const s16x8*)t1, bt11 = *(const s16x8*)(t1+32);
  f32x4 acc[2][4];
  #pragma unroll
  for(int n2=0;n2<2;++n2)
    #pragma unroll
    for(int ct=0;ct<4;++ct) acc[n2][ct] = (f32x4){0.f,0.f,0.f,0.f};

  const int mcnt = NTOK/MSPLIT;
  const int NCH = mcnt/32;
  const int ch0 = (mpart*mcnt)/32;

  const int srl = wq*8 + (lane>>3);
  const int ssl = (lane&7) ^ (srl&7);
  auto STAGE_PH = [&](int ci, int bi){
    gload16(phb + (size_t)((ch0+ci)*32 + srl)*CCH + ssl*8,
            ldsPH + bi*2048 + wq*512);
  };

  STAGE_PH(0, 0); SBAR();
  STAGE_PH(1, 1); SBAR();
  #pragma unroll 1
  for(int t=0; t<NCH; ++t){
    WAITVM(1);
    __builtin_amdgcn_s_barrier();
    // G2 register loads for chunk t (4 x b128, 4x256B dense per wave)
    const u16* gp = g2b + ((size_t)((ch0+t)*4 + lg)*CCH + l15)*8;
    s16x8 g0 = *(const s16x8*)(gp);
    s16x8 g1 = *(const s16x8*)(gp + 128);
    s16x8 g2 = *(const s16x8*)(gp + 256);
    s16x8 g3 = *(const s16x8*)(gp + 384);
    SBAR();                                        // pin G before STAGE
    int c2 = t+2; if(c2 >= NCH) c2 -= NCH;
    STAGE_PH(c2, (t+2)&3);
    SBAR();                                        // pin staging before compute
    // A-frags from LDS (XOR-unswizzled b128)
    const u16* bPH = ldsPH + (t&3)*2048;
    const int rx = l15 & 7;
    const u16* rb0 = bPH + l15*64;
    const u16* rb1 = rb0 + 16*64;
    s16x8 ap00 = *(const s16x8*)(rb0 + ((lg     ^ rx)<<3));
    s16x8 ap01 = *(const s16x8*)(rb0 + (((lg+4) ^ rx)<<3));
    s16x8 ap10 = *(const s16x8*)(rb1 + ((lg     ^ rx)<<3));
    s16x8 ap11 = *(const s16x8*)(rb1 + (((lg+4) ^ rx)<<3));
    // S' (transposed): lane holds S[n=l15][m = ms*16 + 4*lg + r]
    f32x4 s00={0.f,0.f,0.f,0.f}, s01={0.f,0.f,0.f,0.f};
    f32x4 s10={0.f,0.f,0.f,0.f}, s11={0.f,0.f,0.f,0.f};
    PRIO(1);
    s00 = mfma16(ap00, bt00, s00); s00 = mfma16(ap01, bt01, s00);
    s01 = mfma16(ap10, bt00, s01); s01 = mfma16(ap11, bt01, s01);
    s10 = mfma16(ap00, bt10, s10); s10 = mfma16(ap01, bt11, s10);
    s11 = mfma16(ap10, bt10, s11); s11 = mfma16(ap11, bt11, s11);
    PRIO(0);
    // P = exp2(S') via raw v_exp_f32, packed to bf16 (cvt_pk)
    s16x8 pa0, pa1;
    #pragma unroll
    for(int r=0;r<4;++r){
      pa0[r]   = f2bfh(ex2(s00[r]));
      pa0[4+r] = f2bfh(ex2(s01[r]));
      pa1[r]   = f2bfh(ex2(s10[r]));
      pa1[4+r] = f2bfh(ex2(s11[r]));
    }
    // PV (auto-wait here is vmcnt(1): keeps PH(t+2) in flight)
    PRIO(1);
    acc[0][0] = mfma16(pa0, g0, acc[0][0]);
    acc[1][0] = mfma16(pa1, g0, acc[1][0]);
    acc[0][1] = mfma16(pa0, g1, acc[0][1]);
    acc[1][1] = mfma16(pa1, g1, acc[1][1]);
    acc[0][2] = mfma16(pa0, g2, acc[0][2]);
    acc[1][2] = mfma16(pa1, g2, acc[1][2]);
    acc[0][3] = mfma16(pa0, g3, acc[0][3]);
    acc[1][3] = mfma16(pa1, g3, acc[1][3]);
    PRIO(0);
  }

  float* outp = OUTP + ((size_t)(mpart*NB + b)*NTOK)*CCH;
  #pragma unroll
  for(int n2=0;n2<2;++n2)
    #pragma unroll
    for(int ct=0;ct<4;++ct)
      #pragma unroll
      for(int r=0;r<4;++r)
        outp[(size_t)(nbase + n2*16 + lg*4 + r)*CCH + ct*16 + l15] = acc[n2][ct][r];
}

// ---------------------------------------------------------------------------
// Kernel 5a: reduce m-partials. OUTS[i] = sum_h OUTP[h][i]. Pure streaming
// f32x4, fully coalesced, ~32 VGPR, no spill.
// ---------------------------------------------------------------------------
__global__ __launch_bounds__(256) void reduce_kernel(
    const float* __restrict__ OUTP, float* __restrict__ OUTS, int msplit){
  const int gid = blockIdx.x*256 + threadIdx.x;          // f32x4 index
  const size_t stride4 = (size_t)NB*NTOK*CCH/4;
  const f32x4* src = (const f32x4*)OUTP;
  f32x4 a = src[gid];
  for(int h=1; h<msplit; ++h){
    f32x4 u = src[h*stride4 + gid];
    a[0]+=u[0]; a[1]+=u[1]; a[2]+=u[2]; a[3]+=u[3];
  }
  ((f32x4*)OUTS)[gid] = a;
}

// ---------------------------------------------------------------------------
// Kernel 5b: w_mask 1x1 conv + residual. 512 thr = 64 tokens x 8 waves
// (8 output channels each). Per-lane v[16] f32x4 (statically indexed, fits
// registers under __launch_bounds__(512,2)). wm rows via wave-uniform s_loads.
// ---------------------------------------------------------------------------
__global__ __launch_bounds__(512, 2) void conv_kernel(
    const float* __restrict__ OUTS, const float* __restrict__ w_mask,
    const float* __restrict__ x, float* __restrict__ out){
  const int b = blockIdx.y;
  const int nl = threadIdx.x & 63;
  const int n = blockIdx.x*64 + nl;
  const int q = __builtin_amdgcn_readfirstlane((int)(threadIdx.x >> 6)); // 0..7
  const f32x4* vr = (const f32x4*)(OUTS + ((size_t)b*NTOK + n)*CCH);
  f32x4 v[16];
  #pragma unroll
  for(int k=0;k<16;++k) v[k] = vr[k];
  const float* wm = w_mask + q*8*32;       // 8 rows of 32, wave-uniform
  #pragma unroll
  for(int jj=0;jj<8;++jj){
    float a0 = 0.f, a1 = 0.f;
    #pragma unroll
    for(int ic=0;ic<32;++ic){
      float w = wm[jj*32 + ic];
      a0 = fmaf(w, v[ic>>1][(2*ic)&3],   a0);
      a1 = fmaf(w, v[ic>>1][(2*ic+1)&3], a1);
    }
    const size_t idx = ((size_t)b*CCH + q*8 + jj)*HWSZ + n;
    out[idx]        = a0 + x[idx];
    out[idx + NTOK] = a1 + x[idx + NTOK];
  }
}

// ---------------------------------------------------------------------------
extern "C" void kernel_launch(void* const* d_in, const int* in_sizes, int n_in,
                              void* d_out, int out_size, void* d_ws, size_t ws_size,
                              hipStream_t stream){
  const float* x       = (const float*)d_in[0];
  const float* y       = (const float*)d_in[1];
  const float* w_phi   = (const float*)d_in[2];
  const float* w_theta = (const float*)d_in[3];
  const float* w_g     = (const float*)d_in[4];
  const float* w_mask  = (const float*)d_in[5];
  float* out = (float*)d_out;
  char* ws = (char*)d_ws;

  const size_t projB  = (size_t)NB*NTOK*CCH*sizeof(u16);    // 2,359,296
  const size_t outpB1 = (size_t)NB*NTOK*CCH*sizeof(float);  // 4,718,592 per split
  const size_t fstat  = (size_t)NB*NTOK*sizeof(float);      // 73,728
  const size_t fixed  = 4*projB + (size_t)NSPL*fstat + outpB1; // TH,PH,G,G2,stats,OUTS

  int msplit = (ws_size >= fixed + 8*outpB1) ? 8
             : (ws_size >= fixed + 4*outpB1) ? 4 : 2;

  size_t off = 0;
  u16*   TH    = (u16*)(ws + off); off += projB;
  u16*   PH    = (u16*)(ws + off); off += projB;
  u16*   G     = (u16*)(ws + off); off += projB;
  u16*   G2    = (u16*)(ws + off); off += projB;
  float* OUTP  = (float*)(ws + off); off += (size_t)msplit*outpB1;
  float* OUTS  = (float*)(ws + off); off += outpB1;
  float* CSUMP = (float*)(ws + off); off += (size_t)NSPL*fstat;

  proj_kernel<<<dim3(NTOK/64, NB), 512, 0, stream>>>(x, y, w_phi, w_theta, w_g,
                                                     TH, PH, G);
  passA_kernel<<<dim3((NTOK/128)*NSPL*NB), 256, 0, stream>>>(TH, PH, CSUMP);
  scale_g_kernel<<<dim3(NB*NCHT), 256, 0, stream>>>(G, CSUMP, G2);
  const int gB = (NTOK/128)*msplit*NB;
  switch(msplit){
    case 8: passB_kernel<8><<<dim3(gB),256,0,stream>>>(TH,PH,G2,OUTP); break;
    case 4: passB_kernel<4><<<dim3(gB),256,0,stream>>>(TH,PH,G2,OUTP); break;
    default: passB_kernel<2><<<dim3(gB),256,0,stream>>>(TH,PH,G2,OUTP); break;
  }
  reduce_kernel<<<dim3((NB*NTOK*CCH/4)/256), 256, 0, stream>>>(OUTP, OUTS, msplit);
  conv_kernel<<<dim3(NTOK/64, NB), 512, 0, stream>>>(OUTS, w_mask, x, out);
}

// Round 10
// 98.535 us; speedup vs baseline: 2.7132x; 1.0527x over previous
//
#include <hip/hip_runtime.h>

#define NTOK 4608   // token axis N = H*W/2
#define CCH  64     // feature axis C
#define HWSZ 9216   // H*W
#define NB   4      // batch
#define NSPL 8      // passA n-split
#define NCHT (NTOK/32)   // 144 chunks of 32 m
#define L2E  1.4426950408889634f

typedef unsigned short u16;
typedef __attribute__((ext_vector_type(4))) short s16x4;   // 4 bf16
typedef __attribute__((ext_vector_type(8))) short s16x8;   // 8 bf16
typedef __attribute__((ext_vector_type(4))) float f32x4;

__device__ __forceinline__ f32x4 mfma16(s16x8 a, s16x8 b, f32x4 c){
  return __builtin_amdgcn_mfma_f32_16x16x32_bf16(a, b, c, 0, 0, 0);
}
// HW bf16 convert (RNE; pairs fuse to v_cvt_pk_bf16_f32)
__device__ __forceinline__ short f2bfh(float f){
  __bf16 h = (__bf16)f;
  return (short)__builtin_bit_cast(unsigned short, h);
}
__device__ __forceinline__ float bf2f(u16 h){
  return __uint_as_float(((unsigned int)h) << 16);
}
// raw v_exp_f32 (2^x). Inputs bounded -> no fixup path needed.
__device__ __forceinline__ float ex2(float x){
  return __builtin_amdgcn_exp2f(x);
}

// global -> LDS direct copy, 16B per lane (dest = base + lane*16, linear).
__device__ __forceinline__ void gload16(const void* g, void* l){
  __builtin_amdgcn_global_load_lds(
      (const __attribute__((address_space(1))) void*)g,
      (__attribute__((address_space(3))) void*)l, 16, 0, 0);
}
#define SBAR() __builtin_amdgcn_sched_barrier(0)
#define WAITVM(N) do{ SBAR(); asm volatile("s_waitcnt vmcnt(" #N ")" ::: "memory"); SBAR(); }while(0)
#define PRIO(N) __builtin_amdgcn_s_setprio(N)

// ---------------------------------------------------------------------------
// Kernel 1: fused theta/phi/g projections. theta pre-scaled by log2(e).
// TH/PH[b][pos][c] bf16; G[b][c][m] bf16.
// ---------------------------------------------------------------------------
__global__ __launch_bounds__(512) void proj_kernel(
    const float* __restrict__ x, const float* __restrict__ y,
    const float* __restrict__ w_phi, const float* __restrict__ w_theta,
    const float* __restrict__ w_g,
    u16* __restrict__ TH, u16* __restrict__ PH, u16* __restrict__ G){
  const int b = blockIdx.y;
  const int n = blockIdx.x*64 + (threadIdx.x & 63);
  const int wq = __builtin_amdgcn_readfirstlane((int)(threadIdx.x >> 6)); // 0..7
  const float* xb = x + (size_t)b*CCH*HWSZ;
  const float* yb = y + (size_t)b*CCH*HWSZ;
  const float* wp = w_phi   + wq*4*CCH;
  const float* wt = w_theta + wq*4*CCH;
  const float* wg = w_g     + wq*4*CCH;
  float accP[8], accT[8], accG[8];
  #pragma unroll
  for(int j=0;j<8;++j){ accP[j]=0.f; accT[j]=0.f; accG[j]=0.f; }
  for(int k=0;k<CCH;k+=4){
    float xv0[4], xv1[4], yv0[4], yv1[4];
    #pragma unroll
    for(int u=0;u<4;++u){
      xv0[u] = xb[(size_t)(k+u)*HWSZ + n];
      xv1[u] = xb[(size_t)(k+u)*HWSZ + NTOK + n];
      yv0[u] = yb[(size_t)(k+u)*HWSZ + n];
      yv1[u] = yb[(size_t)(k+u)*HWSZ + NTOK + n];
    }
    #pragma unroll
    for(int u=0;u<4;++u)
      #pragma unroll
      for(int j=0;j<8;++j){
        float xv = (j&1)?xv1[u]:xv0[u];
        accP[j] = fmaf(wp[(j>>1)*CCH + k+u], xv, accP[j]);
        accT[j] = fmaf(wt[(j>>1)*CCH + k+u], (j&1)?yv1[u]:yv0[u], accT[j]);
        accG[j] = fmaf(wg[(j>>1)*CCH + k+u], xv, accG[j]);
      }
  }
  s16x8 vp, vt;
  #pragma unroll
  for(int j=0;j<8;++j){
    vp[j]=f2bfh(accP[j]);
    vt[j]=f2bfh(accT[j]*L2E);          // exp2-domain pre-scale
  }
  *(s16x8*)(PH + ((size_t)b*NTOK + n)*CCH + wq*8) = vp;
  *(s16x8*)(TH + ((size_t)b*NTOK + n)*CCH + wq*8) = vt;
  #pragma unroll
  for(int j=0;j<8;++j)
    G[((size_t)b*CCH + wq*8 + j)*NTOK + n] = f2bfh(accG[j]);
}

// ---------------------------------------------------------------------------
// Kernel 2: pass A — per-column sum of exp2(S'). 64-row TH chunks (8KB)
// staged via LDS ring (4 bufs), 2 gloads/wave/chunk, stage-ahead-2,
// counted vmcnt(4), XOR-swizzled b128 reads. 9 chunks -> 9 barriers.
// ---------------------------------------------------------------------------
__global__ __launch_bounds__(256, 4) void passA_kernel(
    const u16* __restrict__ TH, const u16* __restrict__ PH,
    float* __restrict__ CSUMP){
  __shared__ __align__(16) u16 ldsTH[4*4096];     // 4 bufs x 8KB
  const int bid = blockIdx.x;
  const int xcd = bid & 7, b = xcd >> 1;
  const int j = ((bid >> 3) << 1) | (xcd & 1);    // [0, 36*NSPL)
  const int part = j & (NSPL-1);
  const int mt = j >> 3;                           // NSPL == 8
  const int lane = threadIdx.x & 63;
  const int wq = __builtin_amdgcn_readfirstlane((int)(threadIdx.x >> 6));
  const int l15 = lane & 15, lg = lane >> 4;
  const int mbase = mt*128 + wq*32;
  const u16* thb = TH + (size_t)b*NTOK*CCH;
  const u16* phb = PH + (size_t)b*NTOK*CCH;
  const u16* p0 = phb + (size_t)(mbase + l15)*CCH + lg*8;
  const u16* p1 = p0 + 16*CCH;
  s16x8 bf00 = *(const s16x8*)p0, bf01 = *(const s16x8*)(p0+32);
  s16x8 bf10 = *(const s16x8*)p1, bf11 = *(const s16x8*)(p1+32);
  float rs0 = 0.f, rs1 = 0.f;

  const int NCH = (NTOK/NSPL)/64;                  // 9
  const int n0 = part*(NTOK/NSPL);
  // wave stages its 16-row block of the 64-row chunk, in two 8-row gloads.
  const int srl0 = wq*16 + (lane>>3);
  const int ssl0 = (lane&7) ^ (srl0&7);
  const int srl1 = srl0 + 8;
  const int ssl1 = (lane&7) ^ (srl1&7);
  auto STAGE = [&](int ci, int bi){
    const u16* base = thb + (size_t)(n0 + ci*64)*CCH;
    gload16(base + (size_t)srl0*CCH + ssl0*8, ldsTH + bi*4096 + wq*1024);
    gload16(base + (size_t)srl1*CCH + ssl1*8, ldsTH + bi*4096 + wq*1024 + 512);
  };

  STAGE(0, 0); SBAR();
  STAGE(1, 1); SBAR();
  #pragma unroll 1
  for(int t=0; t<NCH; ++t){
    int ci = t+2; if(ci >= NCH) ci -= NCH;         // dummy wrap (data unused)
    STAGE(ci, (t+2)&3);
    WAITVM(4);
    __builtin_amdgcn_s_barrier();
    const u16* bTH = ldsTH + (t&3)*4096;
    #pragma unroll
    for(int s=0;s<4;++s){
      const int r = s*16 + l15, rx = r & 7;
      const u16* rb = bTH + r*64;
      s16x8 a0 = *(const s16x8*)(rb + ((lg     ^ rx)<<3));
      s16x8 a1 = *(const s16x8*)(rb + (((lg+4) ^ rx)<<3));
      f32x4 v0 = {0.f,0.f,0.f,0.f}, v1 = {0.f,0.f,0.f,0.f};
      PRIO(1);
      v0 = mfma16(a0, bf00, v0); v0 = mfma16(a1, bf01, v0);
      v1 = mfma16(a0, bf10, v1); v1 = mfma16(a1, bf11, v1);
      PRIO(0);
      rs0 += (ex2(v0[0])+ex2(v0[1])) + (ex2(v0[2])+ex2(v0[3]));
      rs1 += (ex2(v1[0])+ex2(v1[1])) + (ex2(v1[2])+ex2(v1[3]));
    }
  }

  rs0 += __shfl_xor(rs0, 16); rs0 += __shfl_xor(rs0, 32);
  rs1 += __shfl_xor(rs1, 16); rs1 += __shfl_xor(rs1, 32);
  if(lg == 0){
    float* dst = CSUMP + (size_t)(part*NB + b)*NTOK + mbase;
    dst[l15]      = rs0;
    dst[16 + l15] = rs1;
  }
}

// ---------------------------------------------------------------------------
// Kernel 3: fused stat-merge + G scaling -> G2[b][ch][lg][c][8] PV B-frags.
// ---------------------------------------------------------------------------
__global__ __launch_bounds__(256) void scale_g_kernel(
    const u16* __restrict__ G, const float* __restrict__ CSUMP,
    u16* __restrict__ G2){
  __shared__ float dinv[32];
  const int tid = threadIdx.x;
  const int ch = blockIdx.x % NCHT;
  const int b  = blockIdx.x / NCHT;
  const int m0 = ch*32;
  if(tid < 32){
    float s = 0.f;
    #pragma unroll
    for(int h=0;h<NSPL;++h) s += CSUMP[(size_t)(h*NB+b)*NTOK + m0 + tid];
    dinv[tid] = 1.0f/s;
  }
  __syncthreads();
  const int c  = tid & 63;
  const int lg = tid >> 6;                    // 0..3
  const u16* gr = G + ((size_t)b*CCH + c)*NTOK + m0;
  s16x4 lo = *(const s16x4*)(gr + 4*lg);
  s16x4 hi = *(const s16x4*)(gr + 16 + 4*lg);
  s16x8 o;
  #pragma unroll
  for(int k=0;k<4;++k){
    o[k]   = f2bfh(bf2f((u16)lo[k]) * dinv[4*lg+k]);
    o[4+k] = f2bfh(bf2f((u16)hi[k]) * dinv[16+4*lg+k]);
  }
  *(s16x8*)(G2 + ((((size_t)b*NCHT + ch)*4 + lg)*CCH + c)*8) = o;
}

// ---------------------------------------------------------------------------
// Kernel 4: pass B — PH staged via LDS ring (ahead-2, vmcnt counted);
// G2 fragments register-loaded per chunk; P = exp2(S'); PV into fp32 acc;
// partials stored as bf16 (halves OUTP stream traffic).
// ---------------------------------------------------------------------------
template<int MSPLIT>
__global__ __launch_bounds__(256, 4) void passB_kernel(
    const u16* __restrict__ TH, const u16* __restrict__ PH,
    const u16* __restrict__ G2, u16* __restrict__ OUTPB){
  __shared__ __align__(16) u16 ldsPH[4*2048];
  const int bid = blockIdx.x;
  const int xcd = bid & 7, b = xcd >> 1;
  const int j = ((bid >> 3) << 1) | (xcd & 1);    // [0, 36*MSPLIT)
  const int mpart = j % MSPLIT;
  const int nt = j / MSPLIT;                       // [0, 36)
  const int lane = threadIdx.x & 63;
  const int wq = __builtin_amdgcn_readfirstlane((int)(threadIdx.x >> 6));
  const int l15 = lane & 15, lg = lane >> 4;
  const int nbase = nt*128 + wq*32;
  const u16* thb = TH + (size_t)b*NTOK*CCH;
  const u16* phb = PH + (size_t)b*NTOK*CCH;
  const u16* g2b = G2 + (size_t)b*NCHT*4*CCH*8;
  const u16* t0 = thb + (size_t)(nbase + l15)*CCH + lg*8;
  const u16* t1 = t0 + 16*CCH;
  s16x8 bt00 = *(const s16x8*)t0, bt01 = *(const s16x8*)(t0+32);
  s16x8 bt10 = *(const s16x8*)t1, bt11 = *(const s16x8*)(t1+32);
  f32x4 acc[2][4];
  #pragma unroll
  for(int n2=0;n2<2;++n2)
    #pragma unroll
    for(int ct=0;ct<4;++ct) acc[n2][ct] = (f32x4){0.f,0.f,0.f,0.f};

  const int mcnt = NTOK/MSPLIT;
  const int NCH = mcnt/32;
  const int ch0 = (mpart*mcnt)/32;

  const int srl = wq*8 + (lane>>3);
  const int ssl = (lane&7) ^ (srl&7);
  auto STAGE_PH = [&](int ci, int bi){
    gload16(phb + (size_t)((ch0+ci)*32 + srl)*CCH + ssl*8,
            ldsPH + bi*2048 + wq*512);
  };

  STAGE_PH(0, 0); SBAR();
  STAGE_PH(1, 1); SBAR();
  #pragma unroll 1
  for(int t=0; t<NCH; ++t){
    WAITVM(1);
    __builtin_amdgcn_s_barrier();
    // G2 register loads for chunk t (4 x b128, 4x256B dense per wave)
    const u16* gp = g2b + ((size_t)((ch0+t)*4 + lg)*CCH + l15)*8;
    s16x8 g0 = *(const s16x8*)(gp);
    s16x8 g1 = *(const s16x8*)(gp + 128);
    s16x8 g2 = *(const s16x8*)(gp + 256);
    s16x8 g3 = *(const s16x8*)(gp + 384);
    SBAR();                                        // pin G before STAGE
    int c2 = t+2; if(c2 >= NCH) c2 -= NCH;
    STAGE_PH(c2, (t+2)&3);
    SBAR();                                        // pin staging before compute
    // A-frags from LDS (XOR-unswizzled b128)
    const u16* bPH = ldsPH + (t&3)*2048;
    const int rx = l15 & 7;
    const u16* rb0 = bPH + l15*64;
    const u16* rb1 = rb0 + 16*64;
    s16x8 ap00 = *(const s16x8*)(rb0 + ((lg     ^ rx)<<3));
    s16x8 ap01 = *(const s16x8*)(rb0 + (((lg+4) ^ rx)<<3));
    s16x8 ap10 = *(const s16x8*)(rb1 + ((lg     ^ rx)<<3));
    s16x8 ap11 = *(const s16x8*)(rb1 + (((lg+4) ^ rx)<<3));
    // S' (transposed): lane holds S[n=l15][m = ms*16 + 4*lg + r]
    f32x4 s00={0.f,0.f,0.f,0.f}, s01={0.f,0.f,0.f,0.f};
    f32x4 s10={0.f,0.f,0.f,0.f}, s11={0.f,0.f,0.f,0.f};
    PRIO(1);
    s00 = mfma16(ap00, bt00, s00); s00 = mfma16(ap01, bt01, s00);
    s01 = mfma16(ap10, bt00, s01); s01 = mfma16(ap11, bt01, s01);
    s10 = mfma16(ap00, bt10, s10); s10 = mfma16(ap01, bt11, s10);
    s11 = mfma16(ap10, bt10, s11); s11 = mfma16(ap11, bt11, s11);
    PRIO(0);
    // P = exp2(S') via raw v_exp_f32, packed to bf16 (cvt_pk)
    s16x8 pa0, pa1;
    #pragma unroll
    for(int r=0;r<4;++r){
      pa0[r]   = f2bfh(ex2(s00[r]));
      pa0[4+r] = f2bfh(ex2(s01[r]));
      pa1[r]   = f2bfh(ex2(s10[r]));
      pa1[4+r] = f2bfh(ex2(s11[r]));
    }
    // PV (auto-wait here is counted: keeps PH(t+2) in flight)
    PRIO(1);
    acc[0][0] = mfma16(pa0, g0, acc[0][0]);
    acc[1][0] = mfma16(pa1, g0, acc[1][0]);
    acc[0][1] = mfma16(pa0, g1, acc[0][1]);
    acc[1][1] = mfma16(pa1, g1, acc[1][1]);
    acc[0][2] = mfma16(pa0, g2, acc[0][2]);
    acc[1][2] = mfma16(pa1, g2, acc[1][2]);
    acc[0][3] = mfma16(pa0, g3, acc[0][3]);
    acc[1][3] = mfma16(pa1, g3, acc[1][3]);
    PRIO(0);
  }

  u16* outp = OUTPB + ((size_t)(mpart*NB + b)*NTOK)*CCH;
  #pragma unroll
  for(int n2=0;n2<2;++n2)
    #pragma unroll
    for(int ct=0;ct<4;++ct)
      #pragma unroll
      for(int r=0;r<4;++r)
        outp[(size_t)(nbase + n2*16 + lg*4 + r)*CCH + ct*16 + l15] =
            (u16)f2bfh(acc[n2][ct][r]);
}

// ---------------------------------------------------------------------------
// Kernel 5a: reduce bf16 m-partials -> bf16 OUTS. Pure streaming s16x8.
// ---------------------------------------------------------------------------
__global__ __launch_bounds__(256) void reduce_kernel(
    const u16* __restrict__ OUTPB, u16* __restrict__ OUTS, int msplit){
  const int gid = blockIdx.x*256 + threadIdx.x;          // s16x8 index
  const size_t stride8 = (size_t)NB*NTOK*CCH/8;
  const s16x8* src = (const s16x8*)OUTPB;
  float a[8];
  s16x8 u0 = src[gid];
  #pragma unroll
  for(int k=0;k<8;++k) a[k] = bf2f((u16)u0[k]);
  for(int h=1; h<msplit; ++h){
    s16x8 u = src[(size_t)h*stride8 + gid];
    #pragma unroll
    for(int k=0;k<8;++k) a[k] += bf2f((u16)u[k]);
  }
  s16x8 o;
  #pragma unroll
  for(int k=0;k<8;++k) o[k] = f2bfh(a[k]);
  ((s16x8*)OUTS)[gid] = o;
}

// ---------------------------------------------------------------------------
// Kernel 5b: w_mask 1x1 conv + residual. 512 thr = 64 tokens x 8 waves
// (8 output channels each); OUTS read as bf16, unpacked in registers.
// ---------------------------------------------------------------------------
__global__ __launch_bounds__(512, 2) void conv_kernel(
    const u16* __restrict__ OUTS, const float* __restrict__ w_mask,
    const float* __restrict__ x, float* __restrict__ out){
  const int b = blockIdx.y;
  const int nl = threadIdx.x & 63;
  const int n = blockIdx.x*64 + nl;
  const int q = __builtin_amdgcn_readfirstlane((int)(threadIdx.x >> 6)); // 0..7
  const s16x8* vr = (const s16x8*)(OUTS + ((size_t)b*NTOK + n)*CCH);
  float v[64];
  #pragma unroll
  for(int k=0;k<8;++k){
    s16x8 u = vr[k];
    #pragma unroll
    for(int e=0;e<8;++e) v[k*8+e] = bf2f((u16)u[e]);
  }
  const float* wm = w_mask + q*8*32;       // 8 rows of 32, wave-uniform
  #pragma unroll
  for(int jj=0;jj<8;++jj){
    float a0 = 0.f, a1 = 0.f;
    #pragma unroll
    for(int ic=0;ic<32;++ic){
      float w = wm[jj*32 + ic];
      a0 = fmaf(w, v[2*ic],   a0);
      a1 = fmaf(w, v[2*ic+1], a1);
    }
    const size_t idx = ((size_t)b*CCH + q*8 + jj)*HWSZ + n;
    out[idx]        = a0 + x[idx];
    out[idx + NTOK] = a1 + x[idx + NTOK];
  }
}

// ---------------------------------------------------------------------------
extern "C" void kernel_launch(void* const* d_in, const int* in_sizes, int n_in,
                              void* d_out, int out_size, void* d_ws, size_t ws_size,
                              hipStream_t stream){
  const float* x       = (const float*)d_in[0];
  const float* y       = (const float*)d_in[1];
  const float* w_phi   = (const float*)d_in[2];
  const float* w_theta = (const float*)d_in[3];
  const float* w_g     = (const float*)d_in[4];
  const float* w_mask  = (const float*)d_in[5];
  float* out = (float*)d_out;
  char* ws = (char*)d_ws;

  const size_t projB  = (size_t)NB*NTOK*CCH*sizeof(u16);    // 2,359,296
  const size_t fstat  = (size_t)NB*NTOK*sizeof(float);      // 73,728
  const size_t fixed  = 5*projB + (size_t)NSPL*fstat;   // TH,PH,G,G2,OUTS,stats

  int msplit = (ws_size >= fixed + 8*projB) ? 8
             : (ws_size >= fixed + 4*projB) ? 4 : 2;

  size_t off = 0;
  u16*   TH    = (u16*)(ws + off); off += projB;
  u16*   PH    = (u16*)(ws + off); off += projB;
  u16*   G     = (u16*)(ws + off); off += projB;
  u16*   G2    = (u16*)(ws + off); off += projB;
  u16*   OUTPB = (u16*)(ws + off); off += (size_t)msplit*projB;
  u16*   OUTS  = (u16*)(ws + off); off += projB;
  float* CSUMP = (float*)(ws + off); off += (size_t)NSPL*fstat;

  proj_kernel<<<dim3(NTOK/64, NB), 512, 0, stream>>>(x, y, w_phi, w_theta, w_g,
                                                     TH, PH, G);
  passA_kernel<<<dim3((NTOK/128)*NSPL*NB), 256, 0, stream>>>(TH, PH, CSUMP);
  scale_g_kernel<<<dim3(NB*NCHT), 256, 0, stream>>>(G, CSUMP, G2);
  const int gB = (NTOK/128)*msplit*NB;
  switch(msplit){
    case 8: passB_kernel<8><<<dim3(gB),256,0,stream>>>(TH,PH,G2,OUTPB); break;
    case 4: passB_kernel<4><<<dim3(gB),256,0,stream>>>(TH,PH,G2,OUTPB); break;
    default: passB_kernel<2><<<dim3(gB),256,0,stream>>>(TH,PH,G2,OUTPB); break;
  }
  reduce_kernel<<<dim3((NB*NTOK*CCH/8)/256), 256, 0, stream>>>(OUTPB, OUTS, msplit);
  conv_kernel<<<dim3(NTOK/64, NB), 512, 0, stream>>>(OUTS, w_mask, x, out);
}